// Round 1
// baseline (1045.513 us; speedup 1.0000x reference)
//
#include <hip/hip_runtime.h>
#include <hip/hip_bf16.h>
#include <cstdint>
#include <cstddef>

#define SCAN_CHUNK 2048

__device__ __forceinline__ float leaky02(float x) { return x > 0.f ? x : 0.2f * x; }

// ---------------- CSR build ----------------
__global__ void zero_ints(int* __restrict__ p, int n) {
  int i = blockIdx.x * blockDim.x + threadIdx.x;
  if (i < n) p[i] = 0;
}

__global__ void hist_kernel(const int* __restrict__ dst, int* __restrict__ cnt, int E) {
  int i = blockIdx.x * blockDim.x + threadIdx.x;
  if (i < E) atomicAdd(&cnt[dst[i]], 1);
}

__global__ void scan_pass1(const int* __restrict__ cnt, int* __restrict__ bsum, int n) {
  __shared__ int red[4];
  int b = blockIdx.x, t = threadIdx.x;
  int base = b * SCAN_CHUNK;
  int s = 0;
  for (int i = t; i < SCAN_CHUNK; i += 256) {
    int idx = base + i;
    if (idx < n) s += cnt[idx];
  }
  for (int off = 32; off; off >>= 1) s += __shfl_xor(s, off);
  int lane = t & 63, wid = t >> 6;
  if (lane == 0) red[wid] = s;
  __syncthreads();
  if (t == 0) bsum[b] = red[0] + red[1] + red[2] + red[3];
}

__global__ void scan_pass2(int* __restrict__ bsum, int nb, int* __restrict__ rowp_n) {
  if (threadIdx.x == 0) {
    int run = 0;
    for (int i = 0; i < nb; ++i) { int v = bsum[i]; bsum[i] = run; run += v; }
    *rowp_n = run;   // rowp[N] = E
  }
}

__global__ void scan_pass3(const int* __restrict__ cnt, const int* __restrict__ bsum,
                           int* __restrict__ rowp, int n) {
  __shared__ int wsum[4];
  int b = blockIdx.x, t = threadIdx.x;
  int idx0 = b * SCAN_CHUNK + t * 8;
  int vals[8];
  int s = 0;
#pragma unroll
  for (int i = 0; i < 8; ++i) {
    int id = idx0 + i;
    int v = (id < n) ? cnt[id] : 0;
    vals[i] = s; s += v;
  }
  int lane = t & 63, wid = t >> 6;
  int incl = s;
  for (int off = 1; off < 64; off <<= 1) {
    int o = __shfl_up(incl, off);
    if (lane >= off) incl += o;
  }
  if (lane == 63) wsum[wid] = incl;
  __syncthreads();
  if (t == 0) { int r = 0; for (int i = 0; i < 4; ++i) { int v = wsum[i]; wsum[i] = r; r += v; } }
  __syncthreads();
  int texcl = incl - s + wsum[wid] + bsum[b];
#pragma unroll
  for (int i = 0; i < 8; ++i) {
    int id = idx0 + i;
    if (id < n) rowp[id] = texcl + vals[i];
  }
}

__global__ void scatter_kernel(const int* __restrict__ src, const int* __restrict__ dst,
                               const int* __restrict__ rowp, int* __restrict__ cnt,
                               int* __restrict__ col, int E) {
  int i = blockIdx.x * blockDim.x + threadIdx.x;
  if (i >= E) return;
  int d = dst[i];
  int old = atomicSub(&cnt[d], 1);
  col[rowp[d] + old - 1] = src[i];
}

// ---------------- GEMM: Y[n,NO] = X[n,128] @ W[128,NO] ----------------
template<int NO>
__launch_bounds__(256)
__global__ void gemm_kernel(const float* __restrict__ X, const float* __restrict__ W,
                            float* __restrict__ Y, int n) {
  constexpr int CPT = NO / 32;           // cols per thread (4 or 2)
  __shared__ float sW[128 * NO];
  __shared__ float sX[128 * 64];         // transposed: sX[k][r]
  const int t = threadIdx.x;
  const int r0 = blockIdx.x * 64;

  for (int i = t; i < 128 * NO / 4; i += 256)
    ((float4*)sW)[i] = ((const float4*)W)[i];

  {
    const int rr = t & 63;
    const int kq = t >> 6;               // 0..3
    int gr = r0 + rr; if (gr > n - 1) gr = n - 1;
    const float4* xrow = (const float4*)(X + (size_t)gr * 128);
#pragma unroll
    for (int i = 0; i < 8; ++i) {
      int k4 = kq + i * 4;               // float4 index 0..31
      float4 xv = xrow[k4];
      sX[(k4 * 4 + 0) * 64 + rr] = xv.x;
      sX[(k4 * 4 + 1) * 64 + rr] = xv.y;
      sX[(k4 * 4 + 2) * 64 + rr] = xv.z;
      sX[(k4 * 4 + 3) * 64 + rr] = xv.w;
    }
  }
  __syncthreads();

  const int tx = t & 31, ty = t >> 5;    // ty 0..7 -> 8 rows each
  float acc[8][CPT];
#pragma unroll
  for (int i = 0; i < 8; ++i)
#pragma unroll
    for (int j = 0; j < CPT; ++j) acc[i][j] = 0.f;

#pragma unroll 4
  for (int k = 0; k < 128; ++k) {
    float wv[CPT];
    if constexpr (CPT == 4) {
      float4 w4 = *(const float4*)&sW[k * NO + tx * 4];
      wv[0] = w4.x; wv[1] = w4.y; wv[2] = w4.z; wv[3] = w4.w;
    } else {
      float2 w2 = *(const float2*)&sW[k * NO + tx * 2];
      wv[0] = w2.x; wv[1] = w2.y;
    }
    float4 xa = *(const float4*)&sX[k * 64 + ty * 8];
    float4 xb = *(const float4*)&sX[k * 64 + ty * 8 + 4];
    float xr[8] = {xa.x, xa.y, xa.z, xa.w, xb.x, xb.y, xb.z, xb.w};
#pragma unroll
    for (int i = 0; i < 8; ++i)
#pragma unroll
      for (int j = 0; j < CPT; ++j)
        acc[i][j] = fmaf(xr[i], wv[j], acc[i][j]);
  }

#pragma unroll
  for (int i = 0; i < 8; ++i) {
    int r = r0 + ty * 8 + i;
    if (r < n) {
      float* yp = Y + (size_t)r * NO + tx * CPT;
      if constexpr (CPT == 4) {
        float4 o; o.x = acc[i][0]; o.y = acc[i][1]; o.z = acc[i][2]; o.w = acc[i][3];
        *(float4*)yp = o;
      } else {
        float2 o; o.x = acc[i][0]; o.y = acc[i][1];
        *(float2*)yp = o;
      }
    }
  }
}

// ---------------- attention scalars es/ed ----------------
__global__ void att_scores(const float* __restrict__ xl, const float* __restrict__ as,
                           const float* __restrict__ ad, float* __restrict__ es,
                           float* __restrict__ ed, int n, int H) {
  int gw = (blockIdx.x * blockDim.x + threadIdx.x) >> 6;
  int lane = threadIdx.x & 63;
  if (gw >= n) return;
  const float* row = xl + (size_t)gw * H * 64;
  for (int h = 0; h < H; ++h) {
    float xv = row[h * 64 + lane];
    float v = xv * as[h * 64 + lane];
    float u = xv * ad[h * 64 + lane];
    for (int off = 32; off; off >>= 1) { v += __shfl_xor(v, off); u += __shfl_xor(u, off); }
    if (lane == 0) { es[(size_t)gw * H + h] = v; ed[(size_t)gw * H + h] = u; }
  }
}

// ---------------- aggregation: segment softmax + weighted sum + bias/BN(/ReLU) ----------------
template<int H, bool RELU>
__launch_bounds__(256)
__global__ void aggregate(const float* __restrict__ xl, const float* __restrict__ es,
                          const float* __restrict__ ed, const int* __restrict__ rowp,
                          const int* __restrict__ col, const float* __restrict__ bias,
                          const float* __restrict__ g, const float* __restrict__ be,
                          const float* __restrict__ m, const float* __restrict__ v,
                          float* __restrict__ out, int n) {
  int gw = (blockIdx.x * blockDim.x + threadIdx.x) >> 6;
  int lane = threadIdx.x & 63;
  if (gw >= n * H) return;
  int node, h;
  if constexpr (H == 2) { node = gw >> 1; h = gw & 1; } else { node = gw; h = 0; }
  int beg = rowp[node], end = rowp[node + 1];
  float edv = ed[(size_t)node * H + h];
  float e_self = leaky02(es[(size_t)node * H + h] + edv);

  // pass A: segment max (lanes parallel over edges)
  float mmax = e_self;
  for (int i = beg + lane; i < end; i += 64) {
    int s = col[i];
    mmax = fmaxf(mmax, leaky02(es[(size_t)s * H + h] + edv));
  }
  for (int off = 32; off; off >>= 1) mmax = fmaxf(mmax, __shfl_xor(mmax, off));

  // pass B: weights + channel accumulation (lane = channel)
  float acc = 0.f, den = 0.f;
  for (int base = beg; base < end; base += 64) {
    int idx = base + lane;
    int s = 0; float w = 0.f;
    if (idx < end) {
      s = col[idx];
      w = __expf(leaky02(es[(size_t)s * H + h] + edv) - mmax);
    }
    float wsum = w;
    for (int off = 32; off; off >>= 1) wsum += __shfl_xor(wsum, off);
    den += wsum;
    int cend = end - base; if (cend > 64) cend = 64;
    for (int i = 0; i < cend; ++i) {
      int si = __shfl(s, i);
      float wi = __shfl(w, i);
      acc = fmaf(wi, xl[(size_t)si * (H * 64) + h * 64 + lane], acc);
    }
  }
  // self loop
  float wself = __expf(e_self - mmax);
  den += wself;
  acc = fmaf(wself, xl[(size_t)node * (H * 64) + h * 64 + lane], acc);

  int ch = h * 64 + lane;
  float z = acc / (den + 1e-16f) + bias[ch];
  float sc = rsqrtf(v[ch] + 1e-5f) * g[ch];
  float r = (z - m[ch]) * sc + be[ch];
  if (RELU) r = fmaxf(r, 0.f);
  out[(size_t)node * (H * 64) + ch] = r;
}

extern "C" void kernel_launch(void* const* d_in, const int* in_sizes, int n_in,
                              void* d_out, int out_size, void* d_ws, size_t ws_size,
                              hipStream_t stream) {
  const float* x   = (const float*)d_in[0];
  const int*   ei  = (const int*)d_in[1];
  const float* w1  = (const float*)d_in[2];
  const float* as1 = (const float*)d_in[3];
  const float* ad1 = (const float*)d_in[4];
  const float* b1  = (const float*)d_in[5];
  const float* w2  = (const float*)d_in[6];
  const float* as2 = (const float*)d_in[7];
  const float* ad2 = (const float*)d_in[8];
  const float* b2  = (const float*)d_in[9];
  const float* w3  = (const float*)d_in[10];
  const float* as3 = (const float*)d_in[11];
  const float* ad3 = (const float*)d_in[12];
  const float* b3  = (const float*)d_in[13];
  const float* g1  = (const float*)d_in[14];
  const float* be1 = (const float*)d_in[15];
  const float* m1  = (const float*)d_in[16];
  const float* v1  = (const float*)d_in[17];
  const float* g2  = (const float*)d_in[18];
  const float* be2 = (const float*)d_in[19];
  const float* m2  = (const float*)d_in[20];
  const float* v2  = (const float*)d_in[21];
  const float* g3  = (const float*)d_in[22];
  const float* be3 = (const float*)d_in[23];
  const float* m3  = (const float*)d_in[24];
  const float* v3  = (const float*)d_in[25];

  const int N = in_sizes[0] / 128;
  const int E = in_sizes[1] / 2;
  const int* srcp = ei;
  const int* dstp = ei + E;

  // workspace carve (256B aligned)
  size_t off = 0;
  auto carve = [&](size_t bytes) {
    void* p = (char*)d_ws + off;
    off += (bytes + 255) & ~(size_t)255;
    return p;
  };
  float* A    = (float*)carve((size_t)N * 128 * 4);
  float* B    = (float*)carve((size_t)N * 128 * 4);
  float* esb  = (float*)carve((size_t)N * 2 * 4);
  float* edb  = (float*)carve((size_t)N * 2 * 4);
  int*   cnt  = (int*)carve((size_t)N * 4);
  int*   rowp = (int*)carve((size_t)(N + 1) * 4);
  int*   col  = (int*)carve((size_t)E * 4);
  int*   bsum = (int*)carve(256 * 4);
  (void)ws_size; (void)n_in; (void)out_size;

  const int nb = (N + SCAN_CHUNK - 1) / SCAN_CHUNK;

  // CSR build
  zero_ints<<<(N + 255) / 256, 256, 0, stream>>>(cnt, N);
  hist_kernel<<<(E + 255) / 256, 256, 0, stream>>>(dstp, cnt, E);
  scan_pass1<<<nb, 256, 0, stream>>>(cnt, bsum, N);
  scan_pass2<<<1, 64, 0, stream>>>(bsum, nb, rowp + N);
  scan_pass3<<<nb, 256, 0, stream>>>(cnt, bsum, rowp, N);
  scatter_kernel<<<(E + 255) / 256, 256, 0, stream>>>(srcp, dstp, rowp, cnt, col, E);

  const int gemm_grid = (N + 63) / 64;
  const int row_waves = (N + 3) / 4;        // 4 waves/block, 1 row per wave
  const int agg2_grid = (2 * N + 3) / 4;    // H=2: 2N waves
  const int agg1_grid = (N + 3) / 4;

  // ---- layer 1 ----
  gemm_kernel<128><<<gemm_grid, 256, 0, stream>>>(x, w1, B, N);
  att_scores<<<row_waves, 256, 0, stream>>>(B, as1, ad1, esb, edb, N, 2);
  aggregate<2, true><<<agg2_grid, 256, 0, stream>>>(B, esb, edb, rowp, col, b1, g1, be1, m1, v1, A, N);

  // ---- layer 2 ----
  gemm_kernel<128><<<gemm_grid, 256, 0, stream>>>(A, w2, B, N);
  att_scores<<<row_waves, 256, 0, stream>>>(B, as2, ad2, esb, edb, N, 2);
  aggregate<2, true><<<agg2_grid, 256, 0, stream>>>(B, esb, edb, rowp, col, b2, g2, be2, m2, v2, A, N);

  // ---- layer 3 ----
  gemm_kernel<64><<<gemm_grid, 256, 0, stream>>>(A, w3, B, N);
  att_scores<<<row_waves, 256, 0, stream>>>(B, as3, ad3, esb, edb, N, 1);
  aggregate<1, false><<<agg1_grid, 256, 0, stream>>>(B, esb, edb, rowp, col, b3, g3, be3, m3, v3,
                                                     (float*)d_out, N);
}

// Round 2
// 749.173 us; speedup vs baseline: 1.3956x; 1.3956x over previous
//
#include <hip/hip_runtime.h>
#include <hip/hip_bf16.h>
#include <cstdint>
#include <cstddef>

#define SCAN_CHUNK 2048

__device__ __forceinline__ float leaky02(float x) { return x > 0.f ? x : 0.2f * x; }

// ---------------- CSR build ----------------
__global__ void zero_ints(int* __restrict__ p, int n) {
  int i = blockIdx.x * blockDim.x + threadIdx.x;
  if (i < n) p[i] = 0;
}

__global__ void hist_kernel(const int* __restrict__ dst, int* __restrict__ cnt, int E) {
  int i = blockIdx.x * blockDim.x + threadIdx.x;
  if (i < E) atomicAdd(&cnt[dst[i]], 1);
}

__global__ void scan_pass1(const int* __restrict__ cnt, int* __restrict__ bsum, int n) {
  __shared__ int red[4];
  int b = blockIdx.x, t = threadIdx.x;
  int base = b * SCAN_CHUNK;
  int s = 0;
  for (int i = t; i < SCAN_CHUNK; i += 256) {
    int idx = base + i;
    if (idx < n) s += cnt[idx];
  }
  for (int off = 32; off; off >>= 1) s += __shfl_xor(s, off);
  int lane = t & 63, wid = t >> 6;
  if (lane == 0) red[wid] = s;
  __syncthreads();
  if (t == 0) bsum[b] = red[0] + red[1] + red[2] + red[3];
}

__global__ void scan_pass2(int* __restrict__ bsum, int nb, int* __restrict__ rowp_n) {
  if (threadIdx.x == 0) {
    int run = 0;
    for (int i = 0; i < nb; ++i) { int v = bsum[i]; bsum[i] = run; run += v; }
    *rowp_n = run;   // rowp[N] = E
  }
}

__global__ void scan_pass3(const int* __restrict__ cnt, const int* __restrict__ bsum,
                           int* __restrict__ rowp, int n) {
  __shared__ int wsum[4];
  int b = blockIdx.x, t = threadIdx.x;
  int idx0 = b * SCAN_CHUNK + t * 8;
  int vals[8];
  int s = 0;
#pragma unroll
  for (int i = 0; i < 8; ++i) {
    int id = idx0 + i;
    int v = (id < n) ? cnt[id] : 0;
    vals[i] = s; s += v;
  }
  int lane = t & 63, wid = t >> 6;
  int incl = s;
  for (int off = 1; off < 64; off <<= 1) {
    int o = __shfl_up(incl, off);
    if (lane >= off) incl += o;
  }
  if (lane == 63) wsum[wid] = incl;
  __syncthreads();
  if (t == 0) { int r = 0; for (int i = 0; i < 4; ++i) { int v = wsum[i]; wsum[i] = r; r += v; } }
  __syncthreads();
  int texcl = incl - s + wsum[wid] + bsum[b];
#pragma unroll
  for (int i = 0; i < 8; ++i) {
    int id = idx0 + i;
    if (id < n) rowp[id] = texcl + vals[i];
  }
}

__global__ void scatter_kernel(const int* __restrict__ src, const int* __restrict__ dst,
                               const int* __restrict__ rowp, int* __restrict__ cnt,
                               int* __restrict__ col, int E) {
  int i = blockIdx.x * blockDim.x + threadIdx.x;
  if (i >= E) return;
  int d = dst[i];
  int old = atomicSub(&cnt[d], 1);
  col[rowp[d] + old - 1] = src[i];
}

// ---------------- GEMM: Y[n,NO] = X[n,128] @ W[128,NO], fused es/ed ----------------
template<int NO>
__launch_bounds__(256)
__global__ void gemm_kernel(const float* __restrict__ X, const float* __restrict__ W,
                            float* __restrict__ Y, int n,
                            const float* __restrict__ as, const float* __restrict__ ad,
                            float* __restrict__ es, float* __restrict__ ed) {
  constexpr int CPT = NO / 32;           // cols per thread (4 or 2)
  __shared__ float sW[128 * NO];
  __shared__ float sX[128 * 64];         // transposed: sX[k][r]
  const int t = threadIdx.x;
  const int r0 = blockIdx.x * 64;

  for (int i = t; i < 128 * NO / 4; i += 256)
    ((float4*)sW)[i] = ((const float4*)W)[i];

  {
    const int rr = t & 63;
    const int kq = t >> 6;               // 0..3
    int gr = r0 + rr; if (gr > n - 1) gr = n - 1;
    const float4* xrow = (const float4*)(X + (size_t)gr * 128);
#pragma unroll
    for (int i = 0; i < 8; ++i) {
      int k4 = kq + i * 4;               // float4 index 0..31
      float4 xv = xrow[k4];
      sX[(k4 * 4 + 0) * 64 + rr] = xv.x;
      sX[(k4 * 4 + 1) * 64 + rr] = xv.y;
      sX[(k4 * 4 + 2) * 64 + rr] = xv.z;
      sX[(k4 * 4 + 3) * 64 + rr] = xv.w;
    }
  }
  __syncthreads();

  const int tx = t & 31, ty = t >> 5;    // ty 0..7 -> 8 rows each
  float acc[8][CPT];
#pragma unroll
  for (int i = 0; i < 8; ++i)
#pragma unroll
    for (int j = 0; j < CPT; ++j) acc[i][j] = 0.f;

#pragma unroll 4
  for (int k = 0; k < 128; ++k) {
    float wv[CPT];
    if constexpr (CPT == 4) {
      float4 w4 = *(const float4*)&sW[k * NO + tx * 4];
      wv[0] = w4.x; wv[1] = w4.y; wv[2] = w4.z; wv[3] = w4.w;
    } else {
      float2 w2 = *(const float2*)&sW[k * NO + tx * 2];
      wv[0] = w2.x; wv[1] = w2.y;
    }
    float4 xa = *(const float4*)&sX[k * 64 + ty * 8];
    float4 xb = *(const float4*)&sX[k * 64 + ty * 8 + 4];
    float xr[8] = {xa.x, xa.y, xa.z, xa.w, xb.x, xb.y, xb.z, xb.w};
#pragma unroll
    for (int i = 0; i < 8; ++i)
#pragma unroll
      for (int j = 0; j < CPT; ++j)
        acc[i][j] = fmaf(xr[i], wv[j], acc[i][j]);
  }

  // store Y + fused attention scalars es/ed
#pragma unroll
  for (int i = 0; i < 8; ++i) {
    int r = r0 + ty * 8 + i;
    // partial dot with att vectors (over this thread's CPT cols)
    float ps = 0.f, pd = 0.f;
#pragma unroll
    for (int j = 0; j < CPT; ++j) {
      int ch = tx * CPT + j;
      int c = ch & 63;
      int h = ch >> 6;
      ps = fmaf(acc[i][j], as[h * 64 + c], ps);
      pd = fmaf(acc[i][j], ad[h * 64 + c], pd);
    }
    constexpr int RW = (NO == 128) ? 8 : 16;     // reduce over 16 (per head) or 32 lanes
#pragma unroll
    for (int off = RW; off; off >>= 1) {
      ps += __shfl_xor(ps, off);
      pd += __shfl_xor(pd, off);
    }
    if (r < n) {
      float* yp = Y + (size_t)r * NO + tx * CPT;
      if constexpr (CPT == 4) {
        float4 o; o.x = acc[i][0]; o.y = acc[i][1]; o.z = acc[i][2]; o.w = acc[i][3];
        *(float4*)yp = o;
      } else {
        float2 o; o.x = acc[i][0]; o.y = acc[i][1];
        *(float2*)yp = o;
      }
      if constexpr (NO == 128) {
        int h = tx >> 4;
        if ((tx & 15) == 0) { es[(size_t)r * 2 + h] = ps; ed[(size_t)r * 2 + h] = pd; }
      } else {
        if (tx == 0) { es[r] = ps; ed[r] = pd; }
      }
    }
  }
}

// ---------------- aggregation H=2: softmax (no max pass) + weighted sum + bias/BN/ReLU ----------------
__launch_bounds__(256)
__global__ void aggregate2(const float* __restrict__ xl, const float* __restrict__ es,
                           const float* __restrict__ ed, const int* __restrict__ rowp,
                           const int* __restrict__ col, const float* __restrict__ bias,
                           const float* __restrict__ g, const float* __restrict__ be,
                           const float* __restrict__ m, const float* __restrict__ v,
                           float* __restrict__ out, int n) {
  int node = (blockIdx.x * blockDim.x + threadIdx.x) >> 6;
  int lane = threadIdx.x & 63;
  if (node >= n) return;
  int beg = rowp[node], end = rowp[node + 1];
  float ed0 = ed[(size_t)node * 2];
  float ed1 = ed[(size_t)node * 2 + 1];

  // self loop
  float2 esl = *(const float2*)&es[(size_t)node * 2];
  float ws0 = __expf(leaky02(esl.x + ed0));
  float ws1 = __expf(leaky02(esl.y + ed1));
  float den0 = ws0, den1 = ws1;
  const float* selfr = xl + (size_t)node * 128;
  float acc0 = ws0 * selfr[lane];
  float acc1 = ws1 * selfr[64 + lane];

  for (int base = beg; base < end; base += 64) {
    int idx = base + lane;
    int s = 0; float w0 = 0.f, w1 = 0.f;
    if (idx < end) {
      s = col[idx];
      float2 e2 = *(const float2*)&es[(size_t)s * 2];
      w0 = __expf(leaky02(e2.x + ed0));
      w1 = __expf(leaky02(e2.y + ed1));
    }
    float t0 = w0, t1 = w1;
#pragma unroll
    for (int off = 32; off; off >>= 1) { t0 += __shfl_xor(t0, off); t1 += __shfl_xor(t1, off); }
    den0 += t0; den1 += t1;

    int cend = end - base; if (cend > 64) cend = 64;
    int i = 0;
    for (; i + 1 < cend; i += 2) {
      int sa = __shfl(s, i), sb = __shfl(s, i + 1);
      float wa0 = __shfl(w0, i), wa1 = __shfl(w1, i);
      float wb0 = __shfl(w0, i + 1), wb1 = __shfl(w1, i + 1);
      const float* ra = xl + (size_t)sa * 128;
      const float* rb = xl + (size_t)sb * 128;
      float xa0 = ra[lane], xa1 = ra[64 + lane];
      float xb0 = rb[lane], xb1 = rb[64 + lane];
      acc0 = fmaf(wa0, xa0, acc0); acc1 = fmaf(wa1, xa1, acc1);
      acc0 = fmaf(wb0, xb0, acc0); acc1 = fmaf(wb1, xb1, acc1);
    }
    if (i < cend) {
      int sa = __shfl(s, i);
      float wa0 = __shfl(w0, i), wa1 = __shfl(w1, i);
      const float* ra = xl + (size_t)sa * 128;
      acc0 = fmaf(wa0, ra[lane], acc0);
      acc1 = fmaf(wa1, ra[64 + lane], acc1);
    }
  }

  // epilogue: bias + BN + ReLU, both heads
  {
    int ch = lane;
    float z = acc0 / (den0 + 1e-16f) + bias[ch];
    float sc = rsqrtf(v[ch] + 1e-5f) * g[ch];
    float r = (z - m[ch]) * sc + be[ch];
    out[(size_t)node * 128 + ch] = fmaxf(r, 0.f);
  }
  {
    int ch = 64 + lane;
    float z = acc1 / (den1 + 1e-16f) + bias[ch];
    float sc = rsqrtf(v[ch] + 1e-5f) * g[ch];
    float r = (z - m[ch]) * sc + be[ch];
    out[(size_t)node * 128 + ch] = fmaxf(r, 0.f);
  }
}

// ---------------- aggregation H=1 (layer 3): softmax + weighted sum + bias/BN ----------------
__launch_bounds__(256)
__global__ void aggregate1(const float* __restrict__ xl, const float* __restrict__ es,
                           const float* __restrict__ ed, const int* __restrict__ rowp,
                           const int* __restrict__ col, const float* __restrict__ bias,
                           const float* __restrict__ g, const float* __restrict__ be,
                           const float* __restrict__ m, const float* __restrict__ v,
                           float* __restrict__ out, int n) {
  int node = (blockIdx.x * blockDim.x + threadIdx.x) >> 6;
  int lane = threadIdx.x & 63;
  if (node >= n) return;
  int beg = rowp[node], end = rowp[node + 1];
  float edv = ed[node];

  float wself = __expf(leaky02(es[node] + edv));
  float den = wself;
  float acc = wself * xl[(size_t)node * 64 + lane];

  for (int base = beg; base < end; base += 64) {
    int idx = base + lane;
    int s = 0; float w = 0.f;
    if (idx < end) {
      s = col[idx];
      w = __expf(leaky02(es[s] + edv));
    }
    float t0 = w;
#pragma unroll
    for (int off = 32; off; off >>= 1) t0 += __shfl_xor(t0, off);
    den += t0;

    int cend = end - base; if (cend > 64) cend = 64;
    int i = 0;
    for (; i + 1 < cend; i += 2) {
      int sa = __shfl(s, i), sb = __shfl(s, i + 1);
      float wa = __shfl(w, i), wb = __shfl(w, i + 1);
      float xa = xl[(size_t)sa * 64 + lane];
      float xb = xl[(size_t)sb * 64 + lane];
      acc = fmaf(wa, xa, acc);
      acc = fmaf(wb, xb, acc);
    }
    if (i < cend) {
      int sa = __shfl(s, i);
      float wa = __shfl(w, i);
      acc = fmaf(wa, xl[(size_t)sa * 64 + lane], acc);
    }
  }

  float z = acc / (den + 1e-16f) + bias[lane];
  float sc = rsqrtf(v[lane] + 1e-5f) * g[lane];
  out[(size_t)node * 64 + lane] = (z - m[lane]) * sc + be[lane];
}

extern "C" void kernel_launch(void* const* d_in, const int* in_sizes, int n_in,
                              void* d_out, int out_size, void* d_ws, size_t ws_size,
                              hipStream_t stream) {
  const float* x   = (const float*)d_in[0];
  const int*   ei  = (const int*)d_in[1];
  const float* w1  = (const float*)d_in[2];
  const float* as1 = (const float*)d_in[3];
  const float* ad1 = (const float*)d_in[4];
  const float* b1  = (const float*)d_in[5];
  const float* w2  = (const float*)d_in[6];
  const float* as2 = (const float*)d_in[7];
  const float* ad2 = (const float*)d_in[8];
  const float* b2  = (const float*)d_in[9];
  const float* w3  = (const float*)d_in[10];
  const float* as3 = (const float*)d_in[11];
  const float* ad3 = (const float*)d_in[12];
  const float* b3  = (const float*)d_in[13];
  const float* g1  = (const float*)d_in[14];
  const float* be1 = (const float*)d_in[15];
  const float* m1  = (const float*)d_in[16];
  const float* v1  = (const float*)d_in[17];
  const float* g2  = (const float*)d_in[18];
  const float* be2 = (const float*)d_in[19];
  const float* m2  = (const float*)d_in[20];
  const float* v2  = (const float*)d_in[21];
  const float* g3  = (const float*)d_in[22];
  const float* be3 = (const float*)d_in[23];
  const float* m3  = (const float*)d_in[24];
  const float* v3  = (const float*)d_in[25];

  const int N = in_sizes[0] / 128;
  const int E = in_sizes[1] / 2;
  const int* srcp = ei;
  const int* dstp = ei + E;

  // workspace carve (256B aligned)
  size_t off = 0;
  auto carve = [&](size_t bytes) {
    void* p = (char*)d_ws + off;
    off += (bytes + 255) & ~(size_t)255;
    return p;
  };
  float* A    = (float*)carve((size_t)N * 128 * 4);
  float* B    = (float*)carve((size_t)N * 128 * 4);
  float* esb  = (float*)carve((size_t)N * 2 * 4);
  float* edb  = (float*)carve((size_t)N * 2 * 4);
  int*   cnt  = (int*)carve((size_t)N * 4);
  int*   rowp = (int*)carve((size_t)(N + 1) * 4);
  int*   col  = (int*)carve((size_t)E * 4);
  int*   bsum = (int*)carve(256 * 4);
  (void)ws_size; (void)n_in; (void)out_size;

  const int nb = (N + SCAN_CHUNK - 1) / SCAN_CHUNK;

  // CSR build
  zero_ints<<<(N + 255) / 256, 256, 0, stream>>>(cnt, N);
  hist_kernel<<<(E + 255) / 256, 256, 0, stream>>>(dstp, cnt, E);
  scan_pass1<<<nb, 256, 0, stream>>>(cnt, bsum, N);
  scan_pass2<<<1, 64, 0, stream>>>(bsum, nb, rowp + N);
  scan_pass3<<<nb, 256, 0, stream>>>(cnt, bsum, rowp, N);
  scatter_kernel<<<(E + 255) / 256, 256, 0, stream>>>(srcp, dstp, rowp, cnt, col, E);

  const int gemm_grid = (N + 63) / 64;
  const int agg_grid = (N + 3) / 4;       // 1 wave per node, 4 waves/block

  // ---- layer 1 ----
  gemm_kernel<128><<<gemm_grid, 256, 0, stream>>>(x, w1, B, N, as1, ad1, esb, edb);
  aggregate2<<<agg_grid, 256, 0, stream>>>(B, esb, edb, rowp, col, b1, g1, be1, m1, v1, A, N);

  // ---- layer 2 ----
  gemm_kernel<128><<<gemm_grid, 256, 0, stream>>>(A, w2, B, N, as2, ad2, esb, edb);
  aggregate2<<<agg_grid, 256, 0, stream>>>(B, esb, edb, rowp, col, b2, g2, be2, m2, v2, A, N);

  // ---- layer 3 ----
  gemm_kernel<64><<<gemm_grid, 256, 0, stream>>>(A, w3, B, N, as3, ad3, esb, edb);
  aggregate1<<<agg_grid, 256, 0, stream>>>(B, esb, edb, rowp, col, b3, g3, be3, m3, v3,
                                           (float*)d_out, N);
}

// Round 3
// 501.693 us; speedup vs baseline: 2.0840x; 1.4933x over previous
//
#include <hip/hip_runtime.h>
#include <hip/hip_bf16.h>
#include <cstdint>
#include <cstddef>

#define SCAN_CHUNK 2048

typedef short bf16x8 __attribute__((ext_vector_type(8)));
typedef float f32x4 __attribute__((ext_vector_type(4)));

__device__ __forceinline__ float leaky02(float x) { return x > 0.f ? x : 0.2f * x; }
__device__ __forceinline__ float bflo(unsigned u) { return __uint_as_float(u << 16); }
__device__ __forceinline__ float bfhi(unsigned u) { return __uint_as_float(u & 0xFFFF0000u); }
__device__ __forceinline__ unsigned short f2bf(float f) {
  __hip_bfloat16 h = __float2bfloat16(f);
  return *(unsigned short*)&h;
}
__device__ __forceinline__ unsigned pack2bf(float a, float b) {
  return (unsigned)f2bf(a) | ((unsigned)f2bf(b) << 16);
}

// ---------------- CSR build ----------------
__global__ void zero_ints(int* __restrict__ p, int n) {
  int i = blockIdx.x * blockDim.x + threadIdx.x;
  if (i < n) p[i] = 0;
}

__global__ void hist_kernel(const int* __restrict__ dst, int* __restrict__ cnt, int E) {
  int i = blockIdx.x * blockDim.x + threadIdx.x;
  if (i < E) atomicAdd(&cnt[dst[i]], 1);
}

__global__ void scan_pass1(const int* __restrict__ cnt, int* __restrict__ bsum, int n) {
  __shared__ int red[4];
  int b = blockIdx.x, t = threadIdx.x;
  int base = b * SCAN_CHUNK;
  int s = 0;
  for (int i = t; i < SCAN_CHUNK; i += 256) {
    int idx = base + i;
    if (idx < n) s += cnt[idx];
  }
  for (int off = 32; off; off >>= 1) s += __shfl_xor(s, off);
  int lane = t & 63, wid = t >> 6;
  if (lane == 0) red[wid] = s;
  __syncthreads();
  if (t == 0) bsum[b] = red[0] + red[1] + red[2] + red[3];
}

__global__ void scan_pass2(int* __restrict__ bsum, int nb, int* __restrict__ rowp_n) {
  if (threadIdx.x == 0) {
    int run = 0;
    for (int i = 0; i < nb; ++i) { int v = bsum[i]; bsum[i] = run; run += v; }
    *rowp_n = run;
  }
}

__global__ void scan_pass3(const int* __restrict__ cnt, const int* __restrict__ bsum,
                           int* __restrict__ rowp, int n) {
  __shared__ int wsum[4];
  int b = blockIdx.x, t = threadIdx.x;
  int idx0 = b * SCAN_CHUNK + t * 8;
  int vals[8];
  int s = 0;
#pragma unroll
  for (int i = 0; i < 8; ++i) {
    int id = idx0 + i;
    int v = (id < n) ? cnt[id] : 0;
    vals[i] = s; s += v;
  }
  int lane = t & 63, wid = t >> 6;
  int incl = s;
  for (int off = 1; off < 64; off <<= 1) {
    int o = __shfl_up(incl, off);
    if (lane >= off) incl += o;
  }
  if (lane == 63) wsum[wid] = incl;
  __syncthreads();
  if (t == 0) { int r = 0; for (int i = 0; i < 4; ++i) { int v = wsum[i]; wsum[i] = r; r += v; } }
  __syncthreads();
  int texcl = incl - s + wsum[wid] + bsum[b];
#pragma unroll
  for (int i = 0; i < 8; ++i) {
    int id = idx0 + i;
    if (id < n) rowp[id] = texcl + vals[i];
  }
}

__global__ void scatter_kernel(const int* __restrict__ src, const int* __restrict__ dst,
                               const int* __restrict__ rowp, int* __restrict__ cnt,
                               int* __restrict__ col, int E) {
  int i = blockIdx.x * blockDim.x + threadIdx.x;
  if (i >= E) return;
  int d = dst[i];
  int old = atomicSub(&cnt[d], 1);
  col[rowp[d] + old - 1] = src[i];
}

// ---------------- input fp32 -> bf16 ----------------
__global__ void convert_x(const float* __restrict__ x, unsigned* __restrict__ out, int n4) {
  int i = blockIdx.x * blockDim.x + threadIdx.x;   // one float4 -> uint2
  if (i >= n4) return;
  float4 v = ((const float4*)x)[i];
  uint2 o;
  o.x = pack2bf(v.x, v.y);
  o.y = pack2bf(v.z, v.w);
  ((uint2*)out)[i] = o;
}

// ---------------- weights: W[128][NO] fp32 -> Wt[NO][128] bf16 ----------------
__global__ void prep_w(const float* __restrict__ w1, const float* __restrict__ w2,
                       const float* __restrict__ w3,
                       unsigned short* __restrict__ t1, unsigned short* __restrict__ t2,
                       unsigned short* __restrict__ t3) {
  int b = blockIdx.x, t = threadIdx.x;
  const float* W; unsigned short* T; int NO; int e;
  if (b < 64)      { W = w1; T = t1; NO = 128; e = b * 256 + t; }
  else if (b < 128){ W = w2; T = t2; NO = 128; e = (b - 64) * 256 + t; }
  else             { W = w3; T = t3; NO = 64;  e = (b - 128) * 256 + t; }
  int c = e >> 7, k = e & 127;          // e = c*128 + k
  T[c * 128 + k] = f2bf(W[k * NO + c]);
}

// ---------------- MFMA GEMM: Y[n,NO](bf16) = X[n,128](bf16) @ W, fused es/ed ----------------
template<int NO>
__launch_bounds__(256)
__global__ void gemm_mfma(const unsigned short* __restrict__ Xb,
                          const unsigned short* __restrict__ Wt,
                          unsigned short* __restrict__ Y, int n,
                          const float* __restrict__ as, const float* __restrict__ ad,
                          float* __restrict__ es, float* __restrict__ ed) {
  constexpr int NT = NO / 16;
  const int wid = threadIdx.x >> 6, lane = threadIdx.x & 63;
  const int wr0 = (blockIdx.x * 4 + wid) * 32;   // 32 rows per wave
  if (wr0 >= n) return;
  const int cl = lane & 15, kg = lane >> 4;

  int r0c = wr0 + cl;      if (r0c > n - 1) r0c = n - 1;
  int r1c = wr0 + 16 + cl; if (r1c > n - 1) r1c = n - 1;
  const unsigned short* a0p = Xb + (size_t)r0c * 128 + kg * 8;
  const unsigned short* a1p = Xb + (size_t)r1c * 128 + kg * 8;
  const unsigned short* bp  = Wt + (size_t)cl * 128 + kg * 8;

  f32x4 acc[2][NT] = {};
#pragma unroll
  for (int ks = 0; ks < 4; ++ks) {
    bf16x8 a0 = *(const bf16x8*)(a0p + ks * 32);
    bf16x8 a1 = *(const bf16x8*)(a1p + ks * 32);
#pragma unroll
    for (int t = 0; t < NT; ++t) {
      bf16x8 bb = *(const bf16x8*)(bp + t * 16 * 128 + ks * 32);
      acc[0][t] = __builtin_amdgcn_mfma_f32_16x16x32_bf16(a0, bb, acc[0][t], 0, 0, 0);
      acc[1][t] = __builtin_amdgcn_mfma_f32_16x16x32_bf16(a1, bb, acc[1][t], 0, 0, 0);
    }
  }

  // att vectors for my column set (as/ad are flat [H*64] = [NO])
  float asv[NT], adv[NT];
#pragma unroll
  for (int t = 0; t < NT; ++t) { asv[t] = as[t * 16 + cl]; adv[t] = ad[t * 16 + cl]; }

#pragma unroll
  for (int s = 0; s < 2; ++s) {
#pragma unroll
    for (int rg = 0; rg < 4; ++rg) {
      int r = wr0 + s * 16 + kg * 4 + rg;
      float ps0 = 0.f, pd0 = 0.f, ps1 = 0.f, pd1 = 0.f;
#pragma unroll
      for (int t = 0; t < NT; ++t) {
        float a = acc[s][t][rg];
        if (NO == 128 && t >= 4) { ps1 = fmaf(a, asv[t], ps1); pd1 = fmaf(a, adv[t], pd1); }
        else                     { ps0 = fmaf(a, asv[t], ps0); pd0 = fmaf(a, adv[t], pd0); }
      }
#pragma unroll
      for (int o = 8; o; o >>= 1) {
        ps0 += __shfl_xor(ps0, o); pd0 += __shfl_xor(pd0, o);
        if (NO == 128) { ps1 += __shfl_xor(ps1, o); pd1 += __shfl_xor(pd1, o); }
      }
      if (r < n) {
        if (cl == 0) {
          if (NO == 128) {
            es[(size_t)r * 2] = ps0; es[(size_t)r * 2 + 1] = ps1;
            ed[(size_t)r * 2] = pd0; ed[(size_t)r * 2 + 1] = pd1;
          } else {
            es[r] = ps0; ed[r] = pd0;
          }
        }
#pragma unroll
        for (int t = 0; t < NT; ++t)
          Y[(size_t)r * NO + t * 16 + cl] = f2bf(acc[s][t][rg]);
      }
    }
  }
}

// ---------------- aggregation H=2 (bf16 xl): softmax + weighted sum + bias/BN/ReLU -> bf16 ----------------
__launch_bounds__(256)
__global__ void aggregate2(const unsigned short* __restrict__ xl, const float* __restrict__ es,
                           const float* __restrict__ ed, const int* __restrict__ rowp,
                           const int* __restrict__ col, const float* __restrict__ bias,
                           const float* __restrict__ g, const float* __restrict__ be,
                           const float* __restrict__ m, const float* __restrict__ v,
                           unsigned* __restrict__ out, int n) {
  int node = (blockIdx.x * blockDim.x + threadIdx.x) >> 6;
  int lane = threadIdx.x & 63;
  if (node >= n) return;
  int beg = rowp[node], end = rowp[node + 1];
  float2 edv = *(const float2*)&ed[(size_t)node * 2];

  // self loop
  float2 esl = *(const float2*)&es[(size_t)node * 2];
  float ws0 = __expf(leaky02(esl.x + edv.x));
  float ws1 = __expf(leaky02(esl.y + edv.y));
  float den0 = ws0, den1 = ws1;
  float wsel = (lane < 32) ? ws0 : ws1;
  unsigned sv = ((const unsigned*)(xl + (size_t)node * 128))[lane];
  float acc0 = wsel * bflo(sv);
  float acc1 = wsel * bfhi(sv);

  for (int base = beg; base < end; base += 64) {
    int idx = base + lane;
    int s = 0; float w0 = 0.f, w1 = 0.f;
    if (idx < end) {
      s = col[idx];
      float2 e2 = *(const float2*)&es[(size_t)s * 2];
      w0 = __expf(leaky02(e2.x + edv.x));
      w1 = __expf(leaky02(e2.y + edv.y));
    }
    float t0 = w0, t1 = w1;
#pragma unroll
    for (int off = 32; off; off >>= 1) { t0 += __shfl_xor(t0, off); t1 += __shfl_xor(t1, off); }
    den0 += t0; den1 += t1;

    int cend = end - base; if (cend > 64) cend = 64;
    int i = 0;
    for (; i + 1 < cend; i += 2) {
      int sa = __shfl(s, i), sb = __shfl(s, i + 1);
      float wa0 = __shfl(w0, i), wa1 = __shfl(w1, i);
      float wb0 = __shfl(w0, i + 1), wb1 = __shfl(w1, i + 1);
      unsigned va = ((const unsigned*)(xl + (size_t)sa * 128))[lane];
      unsigned vb = ((const unsigned*)(xl + (size_t)sb * 128))[lane];
      float wa = (lane < 32) ? wa0 : wa1;
      float wb = (lane < 32) ? wb0 : wb1;
      acc0 = fmaf(wa, bflo(va), acc0); acc1 = fmaf(wa, bfhi(va), acc1);
      acc0 = fmaf(wb, bflo(vb), acc0); acc1 = fmaf(wb, bfhi(vb), acc1);
    }
    if (i < cend) {
      int sa = __shfl(s, i);
      float wa0 = __shfl(w0, i), wa1 = __shfl(w1, i);
      unsigned va = ((const unsigned*)(xl + (size_t)sa * 128))[lane];
      float wa = (lane < 32) ? wa0 : wa1;
      acc0 = fmaf(wa, bflo(va), acc0); acc1 = fmaf(wa, bfhi(va), acc1);
    }
  }

  float denv = (lane < 32) ? den0 : den1;
  float inv = 1.f / (denv + 1e-16f);
  int c0 = 2 * lane, c1 = 2 * lane + 1;
  float z0 = acc0 * inv + bias[c0];
  float z1 = acc1 * inv + bias[c1];
  float r0 = (z0 - m[c0]) * rsqrtf(v[c0] + 1e-5f) * g[c0] + be[c0];
  float r1 = (z1 - m[c1]) * rsqrtf(v[c1] + 1e-5f) * g[c1] + be[c1];
  r0 = fmaxf(r0, 0.f); r1 = fmaxf(r1, 0.f);
  out[(size_t)node * 64 + lane] = pack2bf(r0, r1);
}

// ---------------- aggregation H=1 (bf16 xl, layer 3): -> fp32 d_out ----------------
__launch_bounds__(256)
__global__ void aggregate1(const unsigned short* __restrict__ xl, const float* __restrict__ es,
                           const float* __restrict__ ed, const int* __restrict__ rowp,
                           const int* __restrict__ col, const float* __restrict__ bias,
                           const float* __restrict__ g, const float* __restrict__ be,
                           const float* __restrict__ m, const float* __restrict__ v,
                           float* __restrict__ out, int n) {
  int node = (blockIdx.x * blockDim.x + threadIdx.x) >> 6;
  int lane = threadIdx.x & 63;
  if (node >= n) return;
  int beg = rowp[node], end = rowp[node + 1];
  float edv = ed[node];

  float wself = __expf(leaky02(es[node] + edv));
  float den = wself;
  float acc = wself * __uint_as_float((unsigned)(xl[(size_t)node * 64 + lane]) << 16);

  for (int base = beg; base < end; base += 64) {
    int idx = base + lane;
    int s = 0; float w = 0.f;
    if (idx < end) {
      s = col[idx];
      w = __expf(leaky02(es[s] + edv));
    }
    float t0 = w;
#pragma unroll
    for (int off = 32; off; off >>= 1) t0 += __shfl_xor(t0, off);
    den += t0;

    int cend = end - base; if (cend > 64) cend = 64;
    int i = 0;
    for (; i + 1 < cend; i += 2) {
      int sa = __shfl(s, i), sb = __shfl(s, i + 1);
      float wa = __shfl(w, i), wb = __shfl(w, i + 1);
      float xa = __uint_as_float((unsigned)(xl[(size_t)sa * 64 + lane]) << 16);
      float xb = __uint_as_float((unsigned)(xl[(size_t)sb * 64 + lane]) << 16);
      acc = fmaf(wa, xa, acc);
      acc = fmaf(wb, xb, acc);
    }
    if (i < cend) {
      int sa = __shfl(s, i);
      float wa = __shfl(w, i);
      acc = fmaf(wa, __uint_as_float((unsigned)(xl[(size_t)sa * 64 + lane]) << 16), acc);
    }
  }

  float z = acc / (den + 1e-16f) + bias[lane];
  out[(size_t)node * 64 + lane] = (z - m[lane]) * rsqrtf(v[lane] + 1e-5f) * g[lane] + be[lane];
}

extern "C" void kernel_launch(void* const* d_in, const int* in_sizes, int n_in,
                              void* d_out, int out_size, void* d_ws, size_t ws_size,
                              hipStream_t stream) {
  const float* x   = (const float*)d_in[0];
  const int*   ei  = (const int*)d_in[1];
  const float* w1  = (const float*)d_in[2];
  const float* as1 = (const float*)d_in[3];
  const float* ad1 = (const float*)d_in[4];
  const float* b1  = (const float*)d_in[5];
  const float* w2  = (const float*)d_in[6];
  const float* as2 = (const float*)d_in[7];
  const float* ad2 = (const float*)d_in[8];
  const float* b2  = (const float*)d_in[9];
  const float* w3  = (const float*)d_in[10];
  const float* as3 = (const float*)d_in[11];
  const float* ad3 = (const float*)d_in[12];
  const float* b3  = (const float*)d_in[13];
  const float* g1  = (const float*)d_in[14];
  const float* be1 = (const float*)d_in[15];
  const float* m1  = (const float*)d_in[16];
  const float* v1  = (const float*)d_in[17];
  const float* g2  = (const float*)d_in[18];
  const float* be2 = (const float*)d_in[19];
  const float* m2  = (const float*)d_in[20];
  const float* v2  = (const float*)d_in[21];
  const float* g3  = (const float*)d_in[22];
  const float* be3 = (const float*)d_in[23];
  const float* m3  = (const float*)d_in[24];
  const float* v3  = (const float*)d_in[25];

  const int N = in_sizes[0] / 128;
  const int E = in_sizes[1] / 2;
  const int* srcp = ei;
  const int* dstp = ei + E;

  size_t off = 0;
  auto carve = [&](size_t bytes) {
    void* p = (char*)d_ws + off;
    off += (bytes + 255) & ~(size_t)255;
    return p;
  };
  unsigned short* Xb  = (unsigned short*)carve((size_t)N * 128 * 2);
  unsigned short* Yb  = (unsigned short*)carve((size_t)N * 128 * 2);
  float* esb  = (float*)carve((size_t)N * 2 * 4);
  float* edb  = (float*)carve((size_t)N * 2 * 4);
  int*   cnt  = (int*)carve((size_t)N * 4);
  int*   rowp = (int*)carve((size_t)(N + 1) * 4);
  int*   col  = (int*)carve((size_t)E * 4);
  int*   bsum = (int*)carve(256 * 4);
  unsigned short* Wt1 = (unsigned short*)carve(128 * 128 * 2);
  unsigned short* Wt2 = (unsigned short*)carve(128 * 128 * 2);
  unsigned short* Wt3 = (unsigned short*)carve(128 * 64 * 2);
  (void)ws_size; (void)n_in; (void)out_size;

  const int nb = (N + SCAN_CHUNK - 1) / SCAN_CHUNK;

  // CSR build + input conversion + weight prep
  zero_ints<<<(N + 255) / 256, 256, 0, stream>>>(cnt, N);
  hist_kernel<<<(E + 255) / 256, 256, 0, stream>>>(dstp, cnt, E);
  scan_pass1<<<nb, 256, 0, stream>>>(cnt, bsum, N);
  scan_pass2<<<1, 64, 0, stream>>>(bsum, nb, rowp + N);
  scan_pass3<<<nb, 256, 0, stream>>>(cnt, bsum, rowp, N);
  scatter_kernel<<<(E + 255) / 256, 256, 0, stream>>>(srcp, dstp, rowp, cnt, col, E);
  convert_x<<<(N * 32 + 255) / 256, 256, 0, stream>>>(x, (unsigned*)Xb, N * 32);
  prep_w<<<160, 256, 0, stream>>>(w1, w2, w3, Wt1, Wt2, Wt3);

  const int gemm_grid = (N + 127) / 128;
  const int agg_grid = (N + 3) / 4;

  // ---- layer 1 ----
  gemm_mfma<128><<<gemm_grid, 256, 0, stream>>>(Xb, Wt1, Yb, N, as1, ad1, esb, edb);
  aggregate2<<<agg_grid, 256, 0, stream>>>(Yb, esb, edb, rowp, col, b1, g1, be1, m1, v1,
                                           (unsigned*)Xb, N);
  // ---- layer 2 ----
  gemm_mfma<128><<<gemm_grid, 256, 0, stream>>>(Xb, Wt2, Yb, N, as2, ad2, esb, edb);
  aggregate2<<<agg_grid, 256, 0, stream>>>(Yb, esb, edb, rowp, col, b2, g2, be2, m2, v2,
                                           (unsigned*)Xb, N);
  // ---- layer 3 ----
  gemm_mfma<64><<<gemm_grid, 256, 0, stream>>>(Xb, Wt3, Yb, N, as3, ad3, esb, edb);
  aggregate1<<<agg_grid, 256, 0, stream>>>(Yb, esb, edb, rowp, col, b3, g3, be3, m3, v3,
                                           (float*)d_out, N);
}

// Round 4
// 351.055 us; speedup vs baseline: 2.9782x; 1.4291x over previous
//
#include <hip/hip_runtime.h>
#include <hip/hip_bf16.h>
#include <cstdint>
#include <cstddef>

#define SCAN_CHUNK 2048
#define NBLK 512          // binning blocks
#define BSH 8             // bucket shift: 256 nodes per bucket

typedef short bf16x8 __attribute__((ext_vector_type(8)));
typedef float f32x4 __attribute__((ext_vector_type(4)));

__device__ __forceinline__ float leaky02(float x) { return x > 0.f ? x : 0.2f * x; }
__device__ __forceinline__ float bflo(unsigned u) { return __uint_as_float(u << 16); }
__device__ __forceinline__ float bfhi(unsigned u) { return __uint_as_float(u & 0xFFFF0000u); }
__device__ __forceinline__ unsigned short f2bf(float f) {
  __hip_bfloat16 h = __float2bfloat16(f);
  return *(unsigned short*)&h;
}
__device__ __forceinline__ unsigned pack2bf(float a, float b) {
  return (unsigned)f2bf(a) | ((unsigned)f2bf(b) << 16);
}

// ---------------- generic exclusive scan (3-pass), n up to ~500K ----------------
__global__ void scan_pass1(const int* __restrict__ cnt, int* __restrict__ bsum, int n) {
  __shared__ int red[4];
  int b = blockIdx.x, t = threadIdx.x;
  int base = b * SCAN_CHUNK;
  int s = 0;
  for (int i = t; i < SCAN_CHUNK; i += 256) {
    int idx = base + i;
    if (idx < n) s += cnt[idx];
  }
  for (int off = 32; off; off >>= 1) s += __shfl_xor(s, off);
  int lane = t & 63, wid = t >> 6;
  if (lane == 0) red[wid] = s;
  __syncthreads();
  if (t == 0) bsum[b] = red[0] + red[1] + red[2] + red[3];
}

__global__ void scan_pass2(int* __restrict__ bsum, int nb, int* __restrict__ totp) {
  if (threadIdx.x == 0) {
    int run = 0;
    for (int i = 0; i < nb; ++i) { int v = bsum[i]; bsum[i] = run; run += v; }
    *totp = run;
  }
}

__global__ void scan_pass3(const int* __restrict__ cnt, const int* __restrict__ bsum,
                           int* __restrict__ out, int n) {
  __shared__ int wsum[4];
  int b = blockIdx.x, t = threadIdx.x;
  int idx0 = b * SCAN_CHUNK + t * 8;
  int vals[8];
  int s = 0;
#pragma unroll
  for (int i = 0; i < 8; ++i) {
    int id = idx0 + i;
    int v = (id < n) ? cnt[id] : 0;
    vals[i] = s; s += v;
  }
  int lane = t & 63, wid = t >> 6;
  int incl = s;
  for (int off = 1; off < 64; off <<= 1) {
    int o = __shfl_up(incl, off);
    if (lane >= off) incl += o;
  }
  if (lane == 63) wsum[wid] = incl;
  __syncthreads();
  if (t == 0) { int r = 0; for (int i = 0; i < 4; ++i) { int v = wsum[i]; wsum[i] = r; r += v; } }
  __syncthreads();
  int texcl = incl - s + wsum[wid] + bsum[b];
#pragma unroll
  for (int i = 0; i < 8; ++i) {
    int id = idx0 + i;
    if (id < n) out[id] = texcl + vals[i];
  }
}

// ---------------- bucketed CSR build ----------------
// Phase A: per-block bucket histogram -> H[k*NBLK + b]
__global__ void bucketA(const int* __restrict__ dst, int* __restrict__ H,
                        int E, int NB, int chunk) {
  __shared__ int hist[512];
  int b = blockIdx.x, t = threadIdx.x;
  hist[t] = 0; hist[t + 256] = 0;
  __syncthreads();
  int e0 = b * chunk, e1 = min(E, e0 + chunk);
  for (int e = e0 + t; e < e1; e += 256) atomicAdd(&hist[dst[e] >> BSH], 1);
  __syncthreads();
  for (int k = t; k < NB; k += 256) H[k * NBLK + b] = hist[k];
}

// Phase B: bin edges into bucket-contiguous regions. payload = src | (localdst << 24)
__global__ void bucketB(const int* __restrict__ src, const int* __restrict__ dst,
                        const int* __restrict__ O, unsigned* __restrict__ binned,
                        int E, int NB, int chunk) {
  __shared__ int cur[512];
  int b = blockIdx.x, t = threadIdx.x;
  for (int k = t; k < NB; k += 256) cur[k] = O[k * NBLK + b];
  __syncthreads();
  int e0 = b * chunk, e1 = min(E, e0 + chunk);
  for (int e = e0 + t; e < e1; e += 256) {
    int d = dst[e];
    int k = d >> BSH;
    int pos = atomicAdd(&cur[k], 1);
    binned[pos] = (unsigned)src[e] | ((unsigned)(d & 255) << 24);
  }
}

// Phase C: per-bucket counting sort -> rowp (coalesced) + col (L2-local scatter)
__global__ void bucketC(const unsigned* __restrict__ binned, const int* __restrict__ O,
                        int* __restrict__ rowp, int* __restrict__ col,
                        int N, int E, int NB) {
  __shared__ int cnt2[256];
  __shared__ int cur2[256];
  __shared__ int wsum[4];
  int k = blockIdx.x, t = threadIdx.x;
  int base = O[k * NBLK];
  int end  = (k + 1 < NB) ? O[(k + 1) * NBLK] : E;
  cnt2[t] = 0;
  __syncthreads();
  for (int e = base + t; e < end; e += 256) atomicAdd(&cnt2[binned[e] >> 24], 1);
  __syncthreads();
  int v = cnt2[t];
  int incl = v;
  int lane = t & 63, wid = t >> 6;
  for (int off = 1; off < 64; off <<= 1) {
    int o = __shfl_up(incl, off);
    if (lane >= off) incl += o;
  }
  if (lane == 63) wsum[wid] = incl;
  __syncthreads();
  if (t == 0) { int r = 0; for (int i = 0; i < 4; ++i) { int x = wsum[i]; wsum[i] = r; r += x; } }
  __syncthreads();
  int excl = incl - v + wsum[wid];
  int g = (k << BSH) + t;
  if (g <= N) rowp[g] = base + excl;
  cur2[t] = excl;
  __syncthreads();
  for (int e = base + t; e < end; e += 256) {
    unsigned p = binned[e];
    int pos = atomicAdd(&cur2[p >> 24], 1);
    col[base + pos] = (int)(p & 0xFFFFFFu);
  }
}

// ---------------- input fp32 -> bf16 ----------------
__global__ void convert_x(const float* __restrict__ x, unsigned* __restrict__ out, int n4) {
  int i = blockIdx.x * blockDim.x + threadIdx.x;
  if (i >= n4) return;
  float4 v = ((const float4*)x)[i];
  uint2 o;
  o.x = pack2bf(v.x, v.y);
  o.y = pack2bf(v.z, v.w);
  ((uint2*)out)[i] = o;
}

// ---------------- weights: W[128][NO] fp32 -> Wt[NO][128] bf16 ----------------
__global__ void prep_w(const float* __restrict__ w1, const float* __restrict__ w2,
                       const float* __restrict__ w3,
                       unsigned short* __restrict__ t1, unsigned short* __restrict__ t2,
                       unsigned short* __restrict__ t3) {
  int b = blockIdx.x, t = threadIdx.x;
  const float* W; unsigned short* T; int NO; int e;
  if (b < 64)      { W = w1; T = t1; NO = 128; e = b * 256 + t; }
  else if (b < 128){ W = w2; T = t2; NO = 128; e = (b - 64) * 256 + t; }
  else             { W = w3; T = t3; NO = 64;  e = (b - 128) * 256 + t; }
  int c = e >> 7, k = e & 127;
  T[c * 128 + k] = f2bf(W[k * NO + c]);
}

// ---------------- MFMA GEMM: Y[n,NO](bf16) = X[n,128](bf16) @ W, fused es/ed ----------------
template<int NO>
__launch_bounds__(256)
__global__ void gemm_mfma(const unsigned short* __restrict__ Xb,
                          const unsigned short* __restrict__ Wt,
                          unsigned short* __restrict__ Y, int n,
                          const float* __restrict__ as, const float* __restrict__ ad,
                          float* __restrict__ es, float* __restrict__ ed) {
  constexpr int NT = NO / 16;
  const int wid = threadIdx.x >> 6, lane = threadIdx.x & 63;
  const int wr0 = (blockIdx.x * 4 + wid) * 32;
  if (wr0 >= n) return;
  const int cl = lane & 15, kg = lane >> 4;

  int r0c = wr0 + cl;      if (r0c > n - 1) r0c = n - 1;
  int r1c = wr0 + 16 + cl; if (r1c > n - 1) r1c = n - 1;
  const unsigned short* a0p = Xb + (size_t)r0c * 128 + kg * 8;
  const unsigned short* a1p = Xb + (size_t)r1c * 128 + kg * 8;
  const unsigned short* bp  = Wt + (size_t)cl * 128 + kg * 8;

  f32x4 acc[2][NT] = {};
#pragma unroll
  for (int ks = 0; ks < 4; ++ks) {
    bf16x8 a0 = *(const bf16x8*)(a0p + ks * 32);
    bf16x8 a1 = *(const bf16x8*)(a1p + ks * 32);
#pragma unroll
    for (int t = 0; t < NT; ++t) {
      bf16x8 bb = *(const bf16x8*)(bp + t * 16 * 128 + ks * 32);
      acc[0][t] = __builtin_amdgcn_mfma_f32_16x16x32_bf16(a0, bb, acc[0][t], 0, 0, 0);
      acc[1][t] = __builtin_amdgcn_mfma_f32_16x16x32_bf16(a1, bb, acc[1][t], 0, 0, 0);
    }
  }

  float asv[NT], adv[NT];
#pragma unroll
  for (int t = 0; t < NT; ++t) { asv[t] = as[t * 16 + cl]; adv[t] = ad[t * 16 + cl]; }

#pragma unroll
  for (int s = 0; s < 2; ++s) {
#pragma unroll
    for (int rg = 0; rg < 4; ++rg) {
      int r = wr0 + s * 16 + kg * 4 + rg;
      float ps0 = 0.f, pd0 = 0.f, ps1 = 0.f, pd1 = 0.f;
#pragma unroll
      for (int t = 0; t < NT; ++t) {
        float a = acc[s][t][rg];
        if (NO == 128 && t >= 4) { ps1 = fmaf(a, asv[t], ps1); pd1 = fmaf(a, adv[t], pd1); }
        else                     { ps0 = fmaf(a, asv[t], ps0); pd0 = fmaf(a, adv[t], pd0); }
      }
#pragma unroll
      for (int o = 8; o; o >>= 1) {
        ps0 += __shfl_xor(ps0, o); pd0 += __shfl_xor(pd0, o);
        if (NO == 128) { ps1 += __shfl_xor(ps1, o); pd1 += __shfl_xor(pd1, o); }
      }
      if (r < n) {
        if (cl == 0) {
          if (NO == 128) {
            es[(size_t)r * 2] = ps0; es[(size_t)r * 2 + 1] = ps1;
            ed[(size_t)r * 2] = pd0; ed[(size_t)r * 2 + 1] = pd1;
          } else {
            es[r] = ps0; ed[r] = pd0;
          }
        }
#pragma unroll
        for (int t = 0; t < NT; ++t)
          Y[(size_t)r * NO + t * 16 + cl] = f2bf(acc[s][t][rg]);
      }
    }
  }
}

// ---------------- aggregation H=2: lane-halves, 2 edges per load-step ----------------
__launch_bounds__(256)
__global__ void aggregate2(const unsigned short* __restrict__ xl, const float* __restrict__ es,
                           const float* __restrict__ ed, const int* __restrict__ rowp,
                           const int* __restrict__ col, const float* __restrict__ bias,
                           const float* __restrict__ g, const float* __restrict__ be,
                           const float* __restrict__ m, const float* __restrict__ v,
                           unsigned* __restrict__ out, int n) {
  int node = (blockIdx.x * blockDim.x + threadIdx.x) >> 6;
  int lane = threadIdx.x & 63;
  if (node >= n) return;
  const uint2* xr = (const uint2*)xl;       // row = 32 uint2 (128 bf16)
  int beg = rowp[node], end = rowp[node + 1];
  float2 edv = *(const float2*)&ed[(size_t)node * 2];
  float2 esl = *(const float2*)&es[(size_t)node * 2];
  float ws0 = __expf(leaky02(esl.x + edv.x));
  float ws1 = __expf(leaky02(esl.y + edv.y));
  float den0 = ws0, den1 = ws1;
  const int half = lane >> 5, hl = lane & 31;

  float4 acc = {0.f, 0.f, 0.f, 0.f};
  {
    float wsl = (half == 0) ? ((hl < 16) ? ws0 : ws1) : 0.f;
    uint2 sv = xr[(size_t)node * 32 + hl];
    acc.x = wsl * bflo(sv.x); acc.y = wsl * bfhi(sv.x);
    acc.z = wsl * bflo(sv.y); acc.w = wsl * bfhi(sv.y);
  }

  for (int cb = beg; cb < end; cb += 64) {
    int idx = cb + lane;
    int s = 0; float w0 = 0.f, w1 = 0.f;
    if (idx < end) {
      s = col[idx];
      float2 e2 = *(const float2*)&es[(size_t)s * 2];
      w0 = __expf(leaky02(e2.x + edv.x));
      w1 = __expf(leaky02(e2.y + edv.y));
    }
    float t0 = w0, t1 = w1;
#pragma unroll
    for (int off = 32; off; off >>= 1) { t0 += __shfl_xor(t0, off); t1 += __shfl_xor(t1, off); }
    den0 += t0; den1 += t1;

    int cend = end - cb; if (cend > 64) cend = 64;
    int i = 0;
    for (; i + 4 <= cend; i += 4) {
      int j0 = i + half, j1 = i + 2 + half;
      int s0 = __shfl(s, j0), s1 = __shfl(s, j1);
      float a00 = __shfl(w0, j0), a01 = __shfl(w1, j0);
      float a10 = __shfl(w0, j1), a11 = __shfl(w1, j1);
      uint2 v0 = xr[(size_t)s0 * 32 + hl];
      uint2 v1 = xr[(size_t)s1 * 32 + hl];
      float W0 = (hl < 16) ? a00 : a01;
      float W1 = (hl < 16) ? a10 : a11;
      acc.x = fmaf(W0, bflo(v0.x), acc.x); acc.y = fmaf(W0, bfhi(v0.x), acc.y);
      acc.z = fmaf(W0, bflo(v0.y), acc.z); acc.w = fmaf(W0, bfhi(v0.y), acc.w);
      acc.x = fmaf(W1, bflo(v1.x), acc.x); acc.y = fmaf(W1, bfhi(v1.x), acc.y);
      acc.z = fmaf(W1, bflo(v1.y), acc.z); acc.w = fmaf(W1, bfhi(v1.y), acc.w);
    }
    for (; i < cend; i += 2) {
      int j = i + half;
      int s0 = __shfl(s, j);
      float a00 = __shfl(w0, j), a01 = __shfl(w1, j);
      uint2 v0 = xr[(size_t)s0 * 32 + hl];
      float W0 = (hl < 16) ? a00 : a01;
      acc.x = fmaf(W0, bflo(v0.x), acc.x); acc.y = fmaf(W0, bfhi(v0.x), acc.y);
      acc.z = fmaf(W0, bflo(v0.y), acc.z); acc.w = fmaf(W0, bfhi(v0.y), acc.w);
    }
  }

  acc.x += __shfl_xor(acc.x, 32); acc.y += __shfl_xor(acc.y, 32);
  acc.z += __shfl_xor(acc.z, 32); acc.w += __shfl_xor(acc.w, 32);

  if (half == 0) {
    int c0 = 4 * hl;
    float den = (hl < 16) ? den0 : den1;
    float inv = 1.f / (den + 1e-16f);
    float4 bi = *(const float4*)&bias[c0];
    float4 mm = *(const float4*)&m[c0];
    float4 vv = *(const float4*)&v[c0];
    float4 gg = *(const float4*)&g[c0];
    float4 bb = *(const float4*)&be[c0];
    float r0 = (acc.x * inv + bi.x - mm.x) * rsqrtf(vv.x + 1e-5f) * gg.x + bb.x;
    float r1 = (acc.y * inv + bi.y - mm.y) * rsqrtf(vv.y + 1e-5f) * gg.y + bb.y;
    float r2 = (acc.z * inv + bi.z - mm.z) * rsqrtf(vv.z + 1e-5f) * gg.z + bb.z;
    float r3 = (acc.w * inv + bi.w - mm.w) * rsqrtf(vv.w + 1e-5f) * gg.w + bb.w;
    uint2 o;
    o.x = pack2bf(fmaxf(r0, 0.f), fmaxf(r1, 0.f));
    o.y = pack2bf(fmaxf(r2, 0.f), fmaxf(r3, 0.f));
    ((uint2*)out)[(size_t)node * 32 + hl] = o;
  }
}

// ---------------- aggregation H=1 (layer 3): lane-quarters, 4 edges per load-step ----------------
__launch_bounds__(256)
__global__ void aggregate1(const unsigned short* __restrict__ xl, const float* __restrict__ es,
                           const float* __restrict__ ed, const int* __restrict__ rowp,
                           const int* __restrict__ col, const float* __restrict__ bias,
                           const float* __restrict__ g, const float* __restrict__ be,
                           const float* __restrict__ m, const float* __restrict__ v,
                           float* __restrict__ out, int n) {
  int node = (blockIdx.x * blockDim.x + threadIdx.x) >> 6;
  int lane = threadIdx.x & 63;
  if (node >= n) return;
  const uint2* xr = (const uint2*)xl;       // row = 16 uint2 (64 bf16)
  int beg = rowp[node], end = rowp[node + 1];
  float edv = ed[node];
  float ws = __expf(leaky02(es[node] + edv));
  float den = ws;
  const int qr = lane >> 4, hl = lane & 15;

  float4 acc = {0.f, 0.f, 0.f, 0.f};
  {
    float wsl = (qr == 0) ? ws : 0.f;
    uint2 sv = xr[(size_t)node * 16 + hl];
    acc.x = wsl * bflo(sv.x); acc.y = wsl * bfhi(sv.x);
    acc.z = wsl * bflo(sv.y); acc.w = wsl * bfhi(sv.y);
  }

  for (int cb = beg; cb < end; cb += 64) {
    int idx = cb + lane;
    int s = 0; float w = 0.f;
    if (idx < end) {
      s = col[idx];
      w = __expf(leaky02(es[s] + edv));
    }
    float t0 = w;
#pragma unroll
    for (int off = 32; off; off >>= 1) t0 += __shfl_xor(t0, off);
    den += t0;

    int cend = end - cb; if (cend > 64) cend = 64;
    int i = 0;
    for (; i + 8 <= cend; i += 8) {
      int j0 = i + qr, j1 = i + 4 + qr;
      int s0 = __shfl(s, j0), s1 = __shfl(s, j1);
      float W0 = __shfl(w, j0), W1 = __shfl(w, j1);
      uint2 v0 = xr[(size_t)s0 * 16 + hl];
      uint2 v1 = xr[(size_t)s1 * 16 + hl];
      acc.x = fmaf(W0, bflo(v0.x), acc.x); acc.y = fmaf(W0, bfhi(v0.x), acc.y);
      acc.z = fmaf(W0, bflo(v0.y), acc.z); acc.w = fmaf(W0, bfhi(v0.y), acc.w);
      acc.x = fmaf(W1, bflo(v1.x), acc.x); acc.y = fmaf(W1, bfhi(v1.x), acc.y);
      acc.z = fmaf(W1, bflo(v1.y), acc.z); acc.w = fmaf(W1, bfhi(v1.y), acc.w);
    }
    for (; i < cend; i += 4) {
      int j = i + qr;
      int s0 = __shfl(s, j);
      float W0 = __shfl(w, j);
      uint2 v0 = xr[(size_t)s0 * 16 + hl];
      acc.x = fmaf(W0, bflo(v0.x), acc.x); acc.y = fmaf(W0, bfhi(v0.x), acc.y);
      acc.z = fmaf(W0, bflo(v0.y), acc.z); acc.w = fmaf(W0, bfhi(v0.y), acc.w);
    }
  }

  acc.x += __shfl_xor(acc.x, 16); acc.y += __shfl_xor(acc.y, 16);
  acc.z += __shfl_xor(acc.z, 16); acc.w += __shfl_xor(acc.w, 16);
  acc.x += __shfl_xor(acc.x, 32); acc.y += __shfl_xor(acc.y, 32);
  acc.z += __shfl_xor(acc.z, 32); acc.w += __shfl_xor(acc.w, 32);

  if (lane < 16) {
    int c0 = 4 * hl;
    float inv = 1.f / (den + 1e-16f);
    float4 bi = *(const float4*)&bias[c0];
    float4 mm = *(const float4*)&m[c0];
    float4 vv = *(const float4*)&v[c0];
    float4 gg = *(const float4*)&g[c0];
    float4 bb = *(const float4*)&be[c0];
    float4 r;
    r.x = (acc.x * inv + bi.x - mm.x) * rsqrtf(vv.x + 1e-5f) * gg.x + bb.x;
    r.y = (acc.y * inv + bi.y - mm.y) * rsqrtf(vv.y + 1e-5f) * gg.y + bb.y;
    r.z = (acc.z * inv + bi.z - mm.z) * rsqrtf(vv.z + 1e-5f) * gg.z + bb.z;
    r.w = (acc.w * inv + bi.w - mm.w) * rsqrtf(vv.w + 1e-5f) * gg.w + bb.w;
    ((float4*)out)[(size_t)node * 16 + hl] = r;
  }
}

extern "C" void kernel_launch(void* const* d_in, const int* in_sizes, int n_in,
                              void* d_out, int out_size, void* d_ws, size_t ws_size,
                              hipStream_t stream) {
  const float* x   = (const float*)d_in[0];
  const int*   ei  = (const int*)d_in[1];
  const float* w1  = (const float*)d_in[2];
  const float* as1 = (const float*)d_in[3];
  const float* ad1 = (const float*)d_in[4];
  const float* b1  = (const float*)d_in[5];
  const float* w2  = (const float*)d_in[6];
  const float* as2 = (const float*)d_in[7];
  const float* ad2 = (const float*)d_in[8];
  const float* b2  = (const float*)d_in[9];
  const float* w3  = (const float*)d_in[10];
  const float* as3 = (const float*)d_in[11];
  const float* ad3 = (const float*)d_in[12];
  const float* b3  = (const float*)d_in[13];
  const float* g1  = (const float*)d_in[14];
  const float* be1 = (const float*)d_in[15];
  const float* m1  = (const float*)d_in[16];
  const float* v1  = (const float*)d_in[17];
  const float* g2  = (const float*)d_in[18];
  const float* be2 = (const float*)d_in[19];
  const float* m2  = (const float*)d_in[20];
  const float* v2  = (const float*)d_in[21];
  const float* g3  = (const float*)d_in[22];
  const float* be3 = (const float*)d_in[23];
  const float* m3  = (const float*)d_in[24];
  const float* v3  = (const float*)d_in[25];

  const int N = in_sizes[0] / 128;
  const int E = in_sizes[1] / 2;
  const int* srcp = ei;
  const int* dstp = ei + E;
  const int NB = (N + 255) >> BSH;          // buckets of 256 nodes
  const int M  = NB * NBLK;                 // flat histogram size
  const int chunk = (E + NBLK - 1) / NBLK;

  size_t off = 0;
  auto carve = [&](size_t bytes) {
    void* p = (char*)d_ws + off;
    off += (bytes + 255) & ~(size_t)255;
    return p;
  };
  unsigned short* Xb  = (unsigned short*)carve((size_t)N * 128 * 2);
  unsigned short* Yb  = (unsigned short*)carve((size_t)N * 128 * 2);
  float* esb  = (float*)carve((size_t)N * 2 * 4);
  float* edb  = (float*)carve((size_t)N * 2 * 4);
  int*   rowp = (int*)carve((size_t)(N + 1) * 4);
  int*   col  = (int*)carve((size_t)E * 4);
  int*   H    = (int*)carve((size_t)M * 4);
  int*   O    = (int*)carve((size_t)M * 4);
  unsigned* binned = (unsigned*)carve((size_t)E * 4);
  int*   bsum = (int*)carve(256 * 4);
  int*   tot  = (int*)carve(4);
  unsigned short* Wt1 = (unsigned short*)carve(128 * 128 * 2);
  unsigned short* Wt2 = (unsigned short*)carve(128 * 128 * 2);
  unsigned short* Wt3 = (unsigned short*)carve(128 * 64 * 2);
  (void)ws_size; (void)n_in; (void)out_size;

  const int nb2 = (M + SCAN_CHUNK - 1) / SCAN_CHUNK;

  // CSR build (bucketed counting sort)
  bucketA<<<NBLK, 256, 0, stream>>>(dstp, H, E, NB, chunk);
  scan_pass1<<<nb2, 256, 0, stream>>>(H, bsum, M);
  scan_pass2<<<1, 64, 0, stream>>>(bsum, nb2, tot);
  scan_pass3<<<nb2, 256, 0, stream>>>(H, bsum, O, M);
  bucketB<<<NBLK, 256, 0, stream>>>(srcp, dstp, O, binned, E, NB, chunk);
  bucketC<<<NB, 256, 0, stream>>>(binned, O, rowp, col, N, E, NB);
  convert_x<<<(N * 32 + 255) / 256, 256, 0, stream>>>(x, (unsigned*)Xb, N * 32);
  prep_w<<<160, 256, 0, stream>>>(w1, w2, w3, Wt1, Wt2, Wt3);

  const int gemm_grid = (N + 127) / 128;
  const int agg_grid = (N + 3) / 4;

  // ---- layer 1 ----
  gemm_mfma<128><<<gemm_grid, 256, 0, stream>>>(Xb, Wt1, Yb, N, as1, ad1, esb, edb);
  aggregate2<<<agg_grid, 256, 0, stream>>>(Yb, esb, edb, rowp, col, b1, g1, be1, m1, v1,
                                           (unsigned*)Xb, N);
  // ---- layer 2 ----
  gemm_mfma<128><<<gemm_grid, 256, 0, stream>>>(Xb, Wt2, Yb, N, as2, ad2, esb, edb);
  aggregate2<<<agg_grid, 256, 0, stream>>>(Yb, esb, edb, rowp, col, b2, g2, be2, m2, v2,
                                           (unsigned*)Xb, N);
  // ---- layer 3 ----
  gemm_mfma<64><<<gemm_grid, 256, 0, stream>>>(Xb, Wt3, Yb, N, as3, ad3, esb, edb);
  aggregate1<<<agg_grid, 256, 0, stream>>>(Yb, esb, edb, rowp, col, b3, g3, be3, m3, v3,
                                           (float*)d_out, N);
}

// Round 5
// 344.517 us; speedup vs baseline: 3.0347x; 1.0190x over previous
//
#include <hip/hip_runtime.h>
#include <hip/hip_bf16.h>
#include <cstdint>
#include <cstddef>

#define SCAN_CHUNK 2048
#define NBLK 512          // binning blocks
#define BSH 8             // bucket shift: 256 nodes per bucket

typedef short bf16x8 __attribute__((ext_vector_type(8)));
typedef float f32x4 __attribute__((ext_vector_type(4)));

__device__ __forceinline__ float leaky02(float x) { return x > 0.f ? x : 0.2f * x; }
__device__ __forceinline__ float bflo(unsigned u) { return __uint_as_float(u << 16); }
__device__ __forceinline__ float bfhi(unsigned u) { return __uint_as_float(u & 0xFFFF0000u); }
__device__ __forceinline__ unsigned short f2bf(float f) {
  __hip_bfloat16 h = __float2bfloat16(f);
  return *(unsigned short*)&h;
}
__device__ __forceinline__ unsigned pack2bf(float a, float b) {
  return (unsigned)f2bf(a) | ((unsigned)f2bf(b) << 16);
}

// ---------------- generic exclusive scan (3-pass) ----------------
__global__ void scan_pass1(const int* __restrict__ cnt, int* __restrict__ bsum, int n) {
  __shared__ int red[4];
  int b = blockIdx.x, t = threadIdx.x;
  int base = b * SCAN_CHUNK;
  int s = 0;
  for (int i = t; i < SCAN_CHUNK; i += 256) {
    int idx = base + i;
    if (idx < n) s += cnt[idx];
  }
  for (int off = 32; off; off >>= 1) s += __shfl_xor(s, off);
  int lane = t & 63, wid = t >> 6;
  if (lane == 0) red[wid] = s;
  __syncthreads();
  if (t == 0) bsum[b] = red[0] + red[1] + red[2] + red[3];
}

__global__ void scan_pass2(int* __restrict__ bsum, int nb, int* __restrict__ totp) {
  if (threadIdx.x == 0) {
    int run = 0;
    for (int i = 0; i < nb; ++i) { int v = bsum[i]; bsum[i] = run; run += v; }
    *totp = run;
  }
}

__global__ void scan_pass3(const int* __restrict__ cnt, const int* __restrict__ bsum,
                           int* __restrict__ out, int n) {
  __shared__ int wsum[4];
  int b = blockIdx.x, t = threadIdx.x;
  int idx0 = b * SCAN_CHUNK + t * 8;
  int vals[8];
  int s = 0;
#pragma unroll
  for (int i = 0; i < 8; ++i) {
    int id = idx0 + i;
    int v = (id < n) ? cnt[id] : 0;
    vals[i] = s; s += v;
  }
  int lane = t & 63, wid = t >> 6;
  int incl = s;
  for (int off = 1; off < 64; off <<= 1) {
    int o = __shfl_up(incl, off);
    if (lane >= off) incl += o;
  }
  if (lane == 63) wsum[wid] = incl;
  __syncthreads();
  if (t == 0) { int r = 0; for (int i = 0; i < 4; ++i) { int v = wsum[i]; wsum[i] = r; r += v; } }
  __syncthreads();
  int texcl = incl - s + wsum[wid] + bsum[b];
#pragma unroll
  for (int i = 0; i < 8; ++i) {
    int id = idx0 + i;
    if (id < n) out[id] = texcl + vals[i];
  }
}

// ---------------- bucketed CSR build (self-loops folded in) ----------------
__global__ void bucketA(const int* __restrict__ dst, int* __restrict__ H,
                        int E, int N, int NB, int echunk, int nchunk) {
  __shared__ int hist[512];
  int b = blockIdx.x, t = threadIdx.x;
  hist[t] = 0; hist[t + 256] = 0;
  __syncthreads();
  int e0 = b * echunk, e1 = min(E, e0 + echunk);
  for (int e = e0 + t; e < e1; e += 256) atomicAdd(&hist[dst[e] >> BSH], 1);
  int n0 = b * nchunk, n1 = min(N, n0 + nchunk);
  for (int nn = n0 + t; nn < n1; nn += 256) atomicAdd(&hist[nn >> BSH], 1);
  __syncthreads();
  for (int k = t; k < NB; k += 256) H[k * NBLK + b] = hist[k];
}

__global__ void bucketB(const int* __restrict__ src, const int* __restrict__ dst,
                        const int* __restrict__ O, unsigned* __restrict__ binned,
                        int E, int N, int NB, int echunk, int nchunk) {
  __shared__ int cur[512];
  int b = blockIdx.x, t = threadIdx.x;
  for (int k = t; k < NB; k += 256) cur[k] = O[k * NBLK + b];
  __syncthreads();
  int e0 = b * echunk, e1 = min(E, e0 + echunk);
  for (int e = e0 + t; e < e1; e += 256) {
    int d = dst[e];
    int k = d >> BSH;
    int pos = atomicAdd(&cur[k], 1);
    binned[pos] = (unsigned)src[e] | ((unsigned)(d & 255) << 24);
  }
  int n0 = b * nchunk, n1 = min(N, n0 + nchunk);
  for (int nn = n0 + t; nn < n1; nn += 256) {
    int k = nn >> BSH;
    int pos = atomicAdd(&cur[k], 1);
    binned[pos] = (unsigned)nn | ((unsigned)(nn & 255) << 24);
  }
}

__global__ void bucketC(const unsigned* __restrict__ binned, const int* __restrict__ O,
                        int* __restrict__ rowp, int* __restrict__ col,
                        int N, int Etot, int NB) {
  __shared__ int cnt2[256];
  __shared__ int cur2[256];
  __shared__ int wsum[4];
  int k = blockIdx.x, t = threadIdx.x;
  int base = O[k * NBLK];
  int end  = (k + 1 < NB) ? O[(k + 1) * NBLK] : Etot;
  cnt2[t] = 0;
  __syncthreads();
  for (int e = base + t; e < end; e += 256) atomicAdd(&cnt2[binned[e] >> 24], 1);
  __syncthreads();
  int v = cnt2[t];
  int incl = v;
  int lane = t & 63, wid = t >> 6;
  for (int off = 1; off < 64; off <<= 1) {
    int o = __shfl_up(incl, off);
    if (lane >= off) incl += o;
  }
  if (lane == 63) wsum[wid] = incl;
  __syncthreads();
  if (t == 0) { int r = 0; for (int i = 0; i < 4; ++i) { int x2 = wsum[i]; wsum[i] = r; r += x2; } }
  __syncthreads();
  int excl = incl - v + wsum[wid];
  int g = (k << BSH) + t;
  if (g <= N) rowp[g] = base + excl;
  cur2[t] = excl;
  __syncthreads();
  for (int e = base + t; e < end; e += 256) {
    unsigned p = binned[e];
    int pos = atomicAdd(&cur2[p >> 24], 1);
    col[base + pos] = (int)(p & 0xFFFFFFu);
  }
}

// ---------------- weights: W[128][NO] fp32 -> Wt[NO][128] bf16 ----------------
__global__ void prep_w(const float* __restrict__ w1, const float* __restrict__ w2,
                       const float* __restrict__ w3,
                       unsigned short* __restrict__ t1, unsigned short* __restrict__ t2,
                       unsigned short* __restrict__ t3) {
  int b = blockIdx.x, t = threadIdx.x;
  const float* W; unsigned short* T; int NO; int e;
  if (b < 64)      { W = w1; T = t1; NO = 128; e = b * 256 + t; }
  else if (b < 128){ W = w2; T = t2; NO = 128; e = (b - 64) * 256 + t; }
  else             { W = w3; T = t3; NO = 64;  e = (b - 128) * 256 + t; }
  int c = e >> 7, k = e & 127;
  T[c * 128 + k] = f2bf(W[k * NO + c]);
}

// ---------------- MFMA GEMM: Y[n,NO](bf16) = X[n,128] @ W, fused es/ed ----------------
template<int NO, bool F32IN>
__launch_bounds__(256)
__global__ void gemm_mfma(const void* __restrict__ Xp,
                          const unsigned short* __restrict__ Wt,
                          unsigned short* __restrict__ Y, int n,
                          const float* __restrict__ as, const float* __restrict__ ad,
                          float* __restrict__ es, float* __restrict__ ed) {
  constexpr int NT = NO / 16;
  const int wid = threadIdx.x >> 6, lane = threadIdx.x & 63;
  const int wr0 = (blockIdx.x * 4 + wid) * 32;
  if (wr0 >= n) return;
  const int cl = lane & 15, kg = lane >> 4;

  int r0c = wr0 + cl;      if (r0c > n - 1) r0c = n - 1;
  int r1c = wr0 + 16 + cl; if (r1c > n - 1) r1c = n - 1;

  f32x4 acc[2][NT] = {};
  const unsigned short* Xb = (const unsigned short*)Xp;
  const float* Xf = (const float*)Xp;

#pragma unroll
  for (int ks = 0; ks < 4; ++ks) {
    bf16x8 a0, a1;
    if constexpr (F32IN) {
      const float* p0 = Xf + (size_t)r0c * 128 + kg * 8 + ks * 32;
      const float* p1 = Xf + (size_t)r1c * 128 + kg * 8 + ks * 32;
      float4 u0 = *(const float4*)p0, u1 = *(const float4*)(p0 + 4);
      float4 w0 = *(const float4*)p1, w1 = *(const float4*)(p1 + 4);
      a0[0] = (short)f2bf(u0.x); a0[1] = (short)f2bf(u0.y); a0[2] = (short)f2bf(u0.z); a0[3] = (short)f2bf(u0.w);
      a0[4] = (short)f2bf(u1.x); a0[5] = (short)f2bf(u1.y); a0[6] = (short)f2bf(u1.z); a0[7] = (short)f2bf(u1.w);
      a1[0] = (short)f2bf(w0.x); a1[1] = (short)f2bf(w0.y); a1[2] = (short)f2bf(w0.z); a1[3] = (short)f2bf(w0.w);
      a1[4] = (short)f2bf(w1.x); a1[5] = (short)f2bf(w1.y); a1[6] = (short)f2bf(w1.z); a1[7] = (short)f2bf(w1.w);
    } else {
      a0 = *(const bf16x8*)(Xb + (size_t)r0c * 128 + kg * 8 + ks * 32);
      a1 = *(const bf16x8*)(Xb + (size_t)r1c * 128 + kg * 8 + ks * 32);
    }
#pragma unroll
    for (int t = 0; t < NT; ++t) {
      bf16x8 bb = *(const bf16x8*)(Wt + (size_t)(cl + t * 16) * 128 + kg * 8 + ks * 32);
      acc[0][t] = __builtin_amdgcn_mfma_f32_16x16x32_bf16(a0, bb, acc[0][t], 0, 0, 0);
      acc[1][t] = __builtin_amdgcn_mfma_f32_16x16x32_bf16(a1, bb, acc[1][t], 0, 0, 0);
    }
  }

  float asv[NT], adv[NT];
#pragma unroll
  for (int t = 0; t < NT; ++t) { asv[t] = as[t * 16 + cl]; adv[t] = ad[t * 16 + cl]; }

#pragma unroll
  for (int s = 0; s < 2; ++s) {
#pragma unroll
    for (int rg = 0; rg < 4; ++rg) {
      int r = wr0 + s * 16 + kg * 4 + rg;
      float ps0 = 0.f, pd0 = 0.f, ps1 = 0.f, pd1 = 0.f;
#pragma unroll
      for (int t = 0; t < NT; ++t) {
        float a = acc[s][t][rg];
        if (NO == 128 && t >= 4) { ps1 = fmaf(a, asv[t], ps1); pd1 = fmaf(a, adv[t], pd1); }
        else                     { ps0 = fmaf(a, asv[t], ps0); pd0 = fmaf(a, adv[t], pd0); }
      }
#pragma unroll
      for (int o = 8; o; o >>= 1) {
        ps0 += __shfl_xor(ps0, o); pd0 += __shfl_xor(pd0, o);
        if (NO == 128) { ps1 += __shfl_xor(ps1, o); pd1 += __shfl_xor(pd1, o); }
      }
      if (r < n) {
        if (cl == 0) {
          if (NO == 128) {
            es[(size_t)r * 2] = ps0; es[(size_t)r * 2 + 1] = ps1;
            ed[(size_t)r * 2] = pd0; ed[(size_t)r * 2 + 1] = pd1;
          } else {
            es[r] = ps0; ed[r] = pd0;
          }
        }
#pragma unroll
        for (int t = 0; t < NT; ++t)
          Y[(size_t)r * NO + t * 16 + cl] = f2bf(acc[s][t][rg]);
      }
    }
  }
}

// ---------------- aggregation H=2: lane-quarters, uint4 rows (4 edges/load) ----------------
__launch_bounds__(256)
__global__ void aggregate2(const unsigned short* __restrict__ xl, const float* __restrict__ es,
                           const float* __restrict__ ed, const int* __restrict__ rowp,
                           const int* __restrict__ col, const float* __restrict__ bias,
                           const float* __restrict__ g, const float* __restrict__ be,
                           const float* __restrict__ m, const float* __restrict__ v,
                           uint4* __restrict__ out, int n) {
  int node = (blockIdx.x * blockDim.x + threadIdx.x) >> 6;
  int lane = threadIdx.x & 63;
  if (node >= n) return;
  const uint4* xr = (const uint4*)xl;       // row = 16 uint4 (128 bf16)
  int beg = rowp[node], end = rowp[node + 1];
  float2 edv = *(const float2*)&ed[(size_t)node * 2];
  const int q = lane >> 4, hl = lane & 15;

  float acc[8] = {0.f, 0.f, 0.f, 0.f, 0.f, 0.f, 0.f, 0.f};
  float dl0 = 0.f, dl1 = 0.f;

  for (int cb = beg; cb < end; cb += 64) {
    int idx = cb + lane;
    int s = 0; float w0 = 0.f, w1 = 0.f;
    if (idx < end) {
      s = col[idx];
      float2 e2 = *(const float2*)&es[(size_t)s * 2];
      w0 = __expf(leaky02(e2.x + edv.x));
      w1 = __expf(leaky02(e2.y + edv.y));
    }
    dl0 += w0; dl1 += w1;
    int cend = end - cb; if (cend > 64) cend = 64;
    int i = 0;
    for (; i + 8 <= cend; i += 8) {
      int j0 = i + q, j1 = i + 4 + q;
      int s0 = __shfl(s, j0), s1 = __shfl(s, j1);
      uint4 v0 = xr[(size_t)s0 * 16 + hl];
      uint4 v1 = xr[(size_t)s1 * 16 + hl];
      float w00 = __shfl(w0, j0), w01 = __shfl(w1, j0);
      float w10 = __shfl(w0, j1), w11 = __shfl(w1, j1);
      float W0 = (hl < 8) ? w00 : w01;
      float W1 = (hl < 8) ? w10 : w11;
      acc[0] = fmaf(W0, bflo(v0.x), acc[0]); acc[1] = fmaf(W0, bfhi(v0.x), acc[1]);
      acc[2] = fmaf(W0, bflo(v0.y), acc[2]); acc[3] = fmaf(W0, bfhi(v0.y), acc[3]);
      acc[4] = fmaf(W0, bflo(v0.z), acc[4]); acc[5] = fmaf(W0, bfhi(v0.z), acc[5]);
      acc[6] = fmaf(W0, bflo(v0.w), acc[6]); acc[7] = fmaf(W0, bfhi(v0.w), acc[7]);
      acc[0] = fmaf(W1, bflo(v1.x), acc[0]); acc[1] = fmaf(W1, bfhi(v1.x), acc[1]);
      acc[2] = fmaf(W1, bflo(v1.y), acc[2]); acc[3] = fmaf(W1, bfhi(v1.y), acc[3]);
      acc[4] = fmaf(W1, bflo(v1.z), acc[4]); acc[5] = fmaf(W1, bfhi(v1.z), acc[5]);
      acc[6] = fmaf(W1, bflo(v1.w), acc[6]); acc[7] = fmaf(W1, bfhi(v1.w), acc[7]);
    }
    for (; i < cend; i += 4) {
      int j = i + q;
      int s0 = __shfl(s, j);
      uint4 v0 = xr[(size_t)s0 * 16 + hl];
      float w00 = __shfl(w0, j), w01 = __shfl(w1, j);
      float W0 = (hl < 8) ? w00 : w01;
      acc[0] = fmaf(W0, bflo(v0.x), acc[0]); acc[1] = fmaf(W0, bfhi(v0.x), acc[1]);
      acc[2] = fmaf(W0, bflo(v0.y), acc[2]); acc[3] = fmaf(W0, bfhi(v0.y), acc[3]);
      acc[4] = fmaf(W0, bflo(v0.z), acc[4]); acc[5] = fmaf(W0, bfhi(v0.z), acc[5]);
      acc[6] = fmaf(W0, bflo(v0.w), acc[6]); acc[7] = fmaf(W0, bfhi(v0.w), acc[7]);
    }
  }

#pragma unroll
  for (int k2 = 0; k2 < 8; ++k2) {
    acc[k2] += __shfl_xor(acc[k2], 16);
    acc[k2] += __shfl_xor(acc[k2], 32);
  }
#pragma unroll
  for (int o = 32; o; o >>= 1) { dl0 += __shfl_xor(dl0, o); dl1 += __shfl_xor(dl1, o); }

  if (q == 0) {
    int c0 = hl * 8;
    float den = (hl < 8) ? dl0 : dl1;
    float inv = 1.f / (den + 1e-16f);
    float4 bi0 = *(const float4*)&bias[c0], bi1 = *(const float4*)&bias[c0 + 4];
    float4 mm0 = *(const float4*)&m[c0],    mm1 = *(const float4*)&m[c0 + 4];
    float4 vv0 = *(const float4*)&v[c0],    vv1 = *(const float4*)&v[c0 + 4];
    float4 gg0 = *(const float4*)&g[c0],    gg1 = *(const float4*)&g[c0 + 4];
    float4 bb0 = *(const float4*)&be[c0],   bb1 = *(const float4*)&be[c0 + 4];
    float r0 = (acc[0] * inv + bi0.x - mm0.x) * rsqrtf(vv0.x + 1e-5f) * gg0.x + bb0.x;
    float r1 = (acc[1] * inv + bi0.y - mm0.y) * rsqrtf(vv0.y + 1e-5f) * gg0.y + bb0.y;
    float r2 = (acc[2] * inv + bi0.z - mm0.z) * rsqrtf(vv0.z + 1e-5f) * gg0.z + bb0.z;
    float r3 = (acc[3] * inv + bi0.w - mm0.w) * rsqrtf(vv0.w + 1e-5f) * gg0.w + bb0.w;
    float r4 = (acc[4] * inv + bi1.x - mm1.x) * rsqrtf(vv1.x + 1e-5f) * gg1.x + bb1.x;
    float r5 = (acc[5] * inv + bi1.y - mm1.y) * rsqrtf(vv1.y + 1e-5f) * gg1.y + bb1.y;
    float r6 = (acc[6] * inv + bi1.z - mm1.z) * rsqrtf(vv1.z + 1e-5f) * gg1.z + bb1.z;
    float r7 = (acc[7] * inv + bi1.w - mm1.w) * rsqrtf(vv1.w + 1e-5f) * gg1.w + bb1.w;
    uint4 o;
    o.x = pack2bf(fmaxf(r0, 0.f), fmaxf(r1, 0.f));
    o.y = pack2bf(fmaxf(r2, 0.f), fmaxf(r3, 0.f));
    o.z = pack2bf(fmaxf(r4, 0.f), fmaxf(r5, 0.f));
    o.w = pack2bf(fmaxf(r6, 0.f), fmaxf(r7, 0.f));
    out[(size_t)node * 16 + hl] = o;
  }
}

// ---------------- aggregation H=1: lane-eighths, uint4 rows (8 edges/load) ----------------
__launch_bounds__(256)
__global__ void aggregate1(const unsigned short* __restrict__ xl, const float* __restrict__ es,
                           const float* __restrict__ ed, const int* __restrict__ rowp,
                           const int* __restrict__ col, const float* __restrict__ bias,
                           const float* __restrict__ g, const float* __restrict__ be,
                           const float* __restrict__ m, const float* __restrict__ v,
                           float* __restrict__ out, int n) {
  int node = (blockIdx.x * blockDim.x + threadIdx.x) >> 6;
  int lane = threadIdx.x & 63;
  if (node >= n) return;
  const uint4* xr = (const uint4*)xl;       // row = 8 uint4 (64 bf16)
  int beg = rowp[node], end = rowp[node + 1];
  float edv = ed[node];
  const int g8 = lane >> 3, hl = lane & 7;

  float acc[8] = {0.f, 0.f, 0.f, 0.f, 0.f, 0.f, 0.f, 0.f};
  float dl = 0.f;

  for (int cb = beg; cb < end; cb += 64) {
    int idx = cb + lane;
    int s = 0; float w = 0.f;
    if (idx < end) {
      s = col[idx];
      w = __expf(leaky02(es[s] + edv));
    }
    dl += w;
    int cend = end - cb; if (cend > 64) cend = 64;
    int i = 0;
    for (; i + 16 <= cend; i += 16) {
      int j0 = i + g8, j1 = i + 8 + g8;
      int s0 = __shfl(s, j0), s1 = __shfl(s, j1);
      uint4 v0 = xr[(size_t)s0 * 8 + hl];
      uint4 v1 = xr[(size_t)s1 * 8 + hl];
      float W0 = __shfl(w, j0), W1 = __shfl(w, j1);
      acc[0] = fmaf(W0, bflo(v0.x), acc[0]); acc[1] = fmaf(W0, bfhi(v0.x), acc[1]);
      acc[2] = fmaf(W0, bflo(v0.y), acc[2]); acc[3] = fmaf(W0, bfhi(v0.y), acc[3]);
      acc[4] = fmaf(W0, bflo(v0.z), acc[4]); acc[5] = fmaf(W0, bfhi(v0.z), acc[5]);
      acc[6] = fmaf(W0, bflo(v0.w), acc[6]); acc[7] = fmaf(W0, bfhi(v0.w), acc[7]);
      acc[0] = fmaf(W1, bflo(v1.x), acc[0]); acc[1] = fmaf(W1, bfhi(v1.x), acc[1]);
      acc[2] = fmaf(W1, bflo(v1.y), acc[2]); acc[3] = fmaf(W1, bfhi(v1.y), acc[3]);
      acc[4] = fmaf(W1, bflo(v1.z), acc[4]); acc[5] = fmaf(W1, bfhi(v1.z), acc[5]);
      acc[6] = fmaf(W1, bflo(v1.w), acc[6]); acc[7] = fmaf(W1, bfhi(v1.w), acc[7]);
    }
    for (; i < cend; i += 8) {
      int j = i + g8;
      int s0 = __shfl(s, j);
      uint4 v0 = xr[(size_t)s0 * 8 + hl];
      float W0 = __shfl(w, j);
      acc[0] = fmaf(W0, bflo(v0.x), acc[0]); acc[1] = fmaf(W0, bfhi(v0.x), acc[1]);
      acc[2] = fmaf(W0, bflo(v0.y), acc[2]); acc[3] = fmaf(W0, bfhi(v0.y), acc[3]);
      acc[4] = fmaf(W0, bflo(v0.z), acc[4]); acc[5] = fmaf(W0, bfhi(v0.z), acc[5]);
      acc[6] = fmaf(W0, bflo(v0.w), acc[6]); acc[7] = fmaf(W0, bfhi(v0.w), acc[7]);
    }
  }

#pragma unroll
  for (int k2 = 0; k2 < 8; ++k2) {
    acc[k2] += __shfl_xor(acc[k2], 8);
    acc[k2] += __shfl_xor(acc[k2], 16);
    acc[k2] += __shfl_xor(acc[k2], 32);
  }
#pragma unroll
  for (int o = 32; o; o >>= 1) dl += __shfl_xor(dl, o);

  if (lane < 8) {
    int c0 = hl * 8;
    float inv = 1.f / (dl + 1e-16f);
    float4 bi0 = *(const float4*)&bias[c0], bi1 = *(const float4*)&bias[c0 + 4];
    float4 mm0 = *(const float4*)&m[c0],    mm1 = *(const float4*)&m[c0 + 4];
    float4 vv0 = *(const float4*)&v[c0],    vv1 = *(const float4*)&v[c0 + 4];
    float4 gg0 = *(const float4*)&g[c0],    gg1 = *(const float4*)&g[c0 + 4];
    float4 bb0 = *(const float4*)&be[c0],   bb1 = *(const float4*)&be[c0 + 4];
    float4 ra, rb;
    ra.x = (acc[0] * inv + bi0.x - mm0.x) * rsqrtf(vv0.x + 1e-5f) * gg0.x + bb0.x;
    ra.y = (acc[1] * inv + bi0.y - mm0.y) * rsqrtf(vv0.y + 1e-5f) * gg0.y + bb0.y;
    ra.z = (acc[2] * inv + bi0.z - mm0.z) * rsqrtf(vv0.z + 1e-5f) * gg0.z + bb0.z;
    ra.w = (acc[3] * inv + bi0.w - mm0.w) * rsqrtf(vv0.w + 1e-5f) * gg0.w + bb0.w;
    rb.x = (acc[4] * inv + bi1.x - mm1.x) * rsqrtf(vv1.x + 1e-5f) * gg1.x + bb1.x;
    rb.y = (acc[5] * inv + bi1.y - mm1.y) * rsqrtf(vv1.y + 1e-5f) * gg1.y + bb1.y;
    rb.z = (acc[6] * inv + bi1.z - mm1.z) * rsqrtf(vv1.z + 1e-5f) * gg1.z + bb1.z;
    rb.w = (acc[7] * inv + bi1.w - mm1.w) * rsqrtf(vv1.w + 1e-5f) * gg1.w + bb1.w;
    float4* op = (float4*)(out + (size_t)node * 64 + c0);
    op[0] = ra; op[1] = rb;
  }
}

extern "C" void kernel_launch(void* const* d_in, const int* in_sizes, int n_in,
                              void* d_out, int out_size, void* d_ws, size_t ws_size,
                              hipStream_t stream) {
  const float* x   = (const float*)d_in[0];
  const int*   ei  = (const int*)d_in[1];
  const float* w1  = (const float*)d_in[2];
  const float* as1 = (const float*)d_in[3];
  const float* ad1 = (const float*)d_in[4];
  const float* b1  = (const float*)d_in[5];
  const float* w2  = (const float*)d_in[6];
  const float* as2 = (const float*)d_in[7];
  const float* ad2 = (const float*)d_in[8];
  const float* b2  = (const float*)d_in[9];
  const float* w3  = (const float*)d_in[10];
  const float* as3 = (const float*)d_in[11];
  const float* ad3 = (const float*)d_in[12];
  const float* b3  = (const float*)d_in[13];
  const float* g1  = (const float*)d_in[14];
  const float* be1 = (const float*)d_in[15];
  const float* m1  = (const float*)d_in[16];
  const float* v1  = (const float*)d_in[17];
  const float* g2  = (const float*)d_in[18];
  const float* be2 = (const float*)d_in[19];
  const float* m2  = (const float*)d_in[20];
  const float* v2  = (const float*)d_in[21];
  const float* g3  = (const float*)d_in[22];
  const float* be3 = (const float*)d_in[23];
  const float* m3  = (const float*)d_in[24];
  const float* v3  = (const float*)d_in[25];

  const int N = in_sizes[0] / 128;
  const int E = in_sizes[1] / 2;
  const int Etot = E + N;                   // self-loops folded in
  const int* srcp = ei;
  const int* dstp = ei + E;
  const int NB = (N + 255) >> BSH;
  const int M  = NB * NBLK;
  const int echunk = (E + NBLK - 1) / NBLK;
  const int nchunk = (N + NBLK - 1) / NBLK;

  size_t off = 0;
  auto carve = [&](size_t bytes) {
    void* p = (char*)d_ws + off;
    off += (bytes + 255) & ~(size_t)255;
    return p;
  };
  unsigned short* Xb  = (unsigned short*)carve((size_t)N * 128 * 2);
  unsigned short* Yb  = (unsigned short*)carve((size_t)N * 128 * 2);
  float* esb  = (float*)carve((size_t)N * 2 * 4);
  float* edb  = (float*)carve((size_t)N * 2 * 4);
  int*   rowp = (int*)carve((size_t)(N + 1) * 4);
  int*   col  = (int*)carve((size_t)Etot * 4);
  int*   H    = (int*)carve((size_t)M * 4);
  int*   O    = (int*)carve((size_t)M * 4);
  unsigned* binned = (unsigned*)carve((size_t)Etot * 4);
  int*   bsum = (int*)carve(256 * 4);
  int*   tot  = (int*)carve(4);
  unsigned short* Wt1 = (unsigned short*)carve(128 * 128 * 2);
  unsigned short* Wt2 = (unsigned short*)carve(128 * 128 * 2);
  unsigned short* Wt3 = (unsigned short*)carve(128 * 64 * 2);
  (void)ws_size; (void)n_in; (void)out_size;

  const int nb2 = (M + SCAN_CHUNK - 1) / SCAN_CHUNK;

  bucketA<<<NBLK, 256, 0, stream>>>(dstp, H, E, N, NB, echunk, nchunk);
  scan_pass1<<<nb2, 256, 0, stream>>>(H, bsum, M);
  scan_pass2<<<1, 64, 0, stream>>>(bsum, nb2, tot);
  scan_pass3<<<nb2, 256, 0, stream>>>(H, bsum, O, M);
  bucketB<<<NBLK, 256, 0, stream>>>(srcp, dstp, O, binned, E, N, NB, echunk, nchunk);
  bucketC<<<NB, 256, 0, stream>>>(binned, O, rowp, col, N, Etot, NB);
  prep_w<<<160, 256, 0, stream>>>(w1, w2, w3, Wt1, Wt2, Wt3);

  const int gemm_grid = (N + 127) / 128;
  const int agg_grid = (N + 3) / 4;

  // ---- layer 1 (fp32 input, conversion fused) ----
  gemm_mfma<128, true><<<gemm_grid, 256, 0, stream>>>(x, Wt1, Yb, N, as1, ad1, esb, edb);
  aggregate2<<<agg_grid, 256, 0, stream>>>(Yb, esb, edb, rowp, col, b1, g1, be1, m1, v1,
                                           (uint4*)Xb, N);
  // ---- layer 2 ----
  gemm_mfma<128, false><<<gemm_grid, 256, 0, stream>>>(Xb, Wt2, Yb, N, as2, ad2, esb, edb);
  aggregate2<<<agg_grid, 256, 0, stream>>>(Yb, esb, edb, rowp, col, b2, g2, be2, m2, v2,
                                           (uint4*)Xb, N);
  // ---- layer 3 ----
  gemm_mfma<64, false><<<gemm_grid, 256, 0, stream>>>(Xb, Wt3, Yb, N, as3, ad3, esb, edb);
  aggregate1<<<agg_grid, 256, 0, stream>>>(Yb, esb, edb, rowp, col, b3, g3, be3, m3, v3,
                                           (float*)d_out, N);
}